// Round 4
// baseline (5552.632 us; speedup 1.0000x reference)
//
#include <hip/hip_runtime.h>

typedef unsigned short u16;
typedef unsigned int u32;
typedef u16 u16x8 __attribute__((ext_vector_type(8)));
typedef u16 u16x4 __attribute__((ext_vector_type(4)));
typedef __bf16 bf16x8 __attribute__((ext_vector_type(8)));
typedef float f32x4 __attribute__((ext_vector_type(4)));

#define B_ 64
#define T_ 256
#define D_ 256
#define H_ 1024
#define G4 4096
#define TC 64            // timesteps per chunk
#define MC 4096          // rows per chunk (B_*TC)
#define NCHUNK 4
#define NFLG 2048        // flags per dispatch: [2 half][8 wave][128 ublk]

// ---------- helpers ----------
__device__ __forceinline__ u16 f2bf(float x) {
  u32 u = __builtin_bit_cast(u32, x);
  u += 0x7fffu + ((u >> 16) & 1u);
  return (u16)(u >> 16);
}
__device__ __forceinline__ float bf2f(u16 h) {
  u32 u = ((u32)h) << 16;
  return __builtin_bit_cast(float, u);
}
__device__ __forceinline__ float sigmoidf_(float x) { return 1.f / (1.f + __expf(-x)); }

__device__ __forceinline__ f32x4 mfma16(u16x8 a, u16x8 b, f32x4 c) {
  return __builtin_amdgcn_mfma_f32_16x16x32_bf16(
      __builtin_bit_cast(bf16x8, a), __builtin_bit_cast(bf16x8, b), c, 0, 0, 0);
}

__device__ __forceinline__ void gl2lds16(const u16* g, u16* l) {
  __builtin_amdgcn_global_load_lds(
      (const __attribute__((address_space(1))) u32*)(const void*)g,
      (__attribute__((address_space(3))) u32*)(void*)l, 16, 0, 0);
}

// device-coherent (write-through past non-coherent L2) 4B store
__device__ __forceinline__ void store4_cc(u16* p, u32 v) {
  asm volatile("global_store_dword %0, %1, off sc0 sc1" :: "v"(p), "v"(v) : "memory");
}
__device__ __forceinline__ void store4_cc_u32(u32* p, u32 v) {
  asm volatile("global_store_dword %0, %1, off sc0 sc1" :: "v"(p), "v"(v) : "memory");
}
__device__ __forceinline__ void waitcnt0() {
  asm volatile("s_waitcnt vmcnt(0)" ::: "memory");
}
__device__ __forceinline__ void lgkm0() {
  asm volatile("s_waitcnt lgkmcnt(0)" ::: "memory");
}

// ---------- split fp32 -> (hi, lo) bf16 planes ----------
__global__ void k_split(const float* __restrict__ src, u16* __restrict__ hi,
                        u16* __restrict__ lo, int n4) {
  int i = blockIdx.x * 256 + threadIdx.x;
  if (i >= n4) return;
  const float4* s4 = (const float4*)src;
  float4 v = s4[i];
  u16 h0 = f2bf(v.x), h1 = f2bf(v.y), h2 = f2bf(v.z), h3 = f2bf(v.w);
  u16x4 hv = {h0, h1, h2, h3};
  u16x4 lv = {f2bf(v.x - bf2f(h0)), f2bf(v.y - bf2f(h1)),
              f2bf(v.z - bf2f(h2)), f2bf(v.w - bf2f(h3))};
  *(u16x4*)(hi + 4 * (size_t)i) = hv;
  *(u16x4*)(lo + 4 * (size_t)i) = lv;
}

// gather one time-chunk of xx ([B,T,D] -> [B*TC, D]) and split planes
__global__ void k_split_x(const float* __restrict__ xx, u16* __restrict__ hi,
                          u16* __restrict__ lo, int t0) {
  int i = blockIdx.x * 256 + threadIdx.x;   // over MC * D_/4
  if (i >= MC * (D_ / 4)) return;
  int row = i >> 6, c4 = i & 63;
  int b = row >> 6, tc = row & 63;
  const float4* s4 = (const float4*)xx;
  float4 v = s4[(size_t)(b * T_ + t0 + tc) * (D_ / 4) + c4];
  u16 h0 = f2bf(v.x), h1 = f2bf(v.y), h2 = f2bf(v.z), h3 = f2bf(v.w);
  u16x4 hv = {h0, h1, h2, h3};
  u16x4 lv = {f2bf(v.x - bf2f(h0)), f2bf(v.y - bf2f(h1)),
              f2bf(v.z - bf2f(h2)), f2bf(v.w - bf2f(h3))};
  *(u16x4*)(hi + 4 * (size_t)i) = hv;
  *(u16x4*)(lo + 4 * (size_t)i) = lv;
}

__global__ void k_addvec(const float* __restrict__ a, const float* __restrict__ b,
                         float* __restrict__ o, int n) {
  int i = blockIdx.x * 256 + threadIdx.x;
  if (i < n) o[i] = a[i] + b[i];
}

// ---------- split-precision GEMM: C[M,N] = A[M,K] * B[N,K]^T + bias (fp32 out) ----
// rec=0: standard C[m][n].
// rec=1/2: recurrent xg layout: idx = ((ublk*64 + t)*4 + gate)*512 + b*8 + uu
//   with unit=n&1023, ublk=unit>>3, uu=unit&7, gate=n>>10.
//   rec=1: A rows b-major (b=m>>6, t=m&63)  [l1 output]
//   rec=2: A rows t-major (t=m>>6, b=m&63)  [h ring]
__global__ __launch_bounds__(256, 2) void k_gemm3(
    const u16* __restrict__ Ah, const u16* __restrict__ Al,
    const u16* __restrict__ Bh, const u16* __restrict__ Bl,
    const float* __restrict__ bias, float* __restrict__ C,
    int M, int N, int K, int rec)
{
  __shared__ __attribute__((aligned(16))) u16 sAh[4096];
  __shared__ __attribute__((aligned(16))) u16 sAl[4096];
  __shared__ __attribute__((aligned(16))) u16 sBh[4096];
  __shared__ __attribute__((aligned(16))) u16 sBl[4096];

  const int tid = threadIdx.x;
  const int lane = tid & 63;
  const int wv = tid >> 6;
  const int wm = wv & 1, wn = wv >> 1;
  const int m0 = blockIdx.x * 128;
  const int n0 = blockIdx.y * 128;

  const int r0 = tid >> 2;
  const int kg = (tid & 3) ^ (r0 & 3);
  const size_t aoff0 = (size_t)(m0 + r0) * K + kg * 8;
  const size_t aoff1 = (size_t)(m0 + r0 + 64) * K + kg * 8;
  const size_t boff0 = (size_t)(n0 + r0) * K + kg * 8;
  const size_t boff1 = (size_t)(n0 + r0 + 64) * K + kg * 8;
  const int lb0 = wv * 512;
  const int lb1 = 2048 + wv * 512;

  const int l15 = lane & 15, l4 = lane >> 4;
  int afo[4], bfo[4];
#pragma unroll
  for (int mt = 0; mt < 4; ++mt) {
    int r = wm * 64 + mt * 16 + l15;
    afo[mt] = (r * 4 + (l4 ^ (r & 3))) * 8;
  }
#pragma unroll
  for (int nt = 0; nt < 4; ++nt) {
    int r = wn * 64 + nt * 16 + l15;
    bfo[nt] = (r * 4 + (l4 ^ (r & 3))) * 8;
  }

  f32x4 acc[4][4] = {};

  for (int k0 = 0; k0 < K; k0 += 32) {
    __syncthreads();
    gl2lds16(Ah + aoff0 + k0, &sAh[lb0]);
    gl2lds16(Ah + aoff1 + k0, &sAh[lb1]);
    gl2lds16(Al + aoff0 + k0, &sAl[lb0]);
    gl2lds16(Al + aoff1 + k0, &sAl[lb1]);
    gl2lds16(Bh + boff0 + k0, &sBh[lb0]);
    gl2lds16(Bh + boff1 + k0, &sBh[lb1]);
    gl2lds16(Bl + boff0 + k0, &sBl[lb0]);
    gl2lds16(Bl + boff1 + k0, &sBl[lb1]);
    __syncthreads();

    u16x8 a_h[4], a_l[4], b_h[4], b_l[4];
#pragma unroll
    for (int i = 0; i < 4; ++i) {
      a_h[i] = *(const u16x8*)&sAh[afo[i]];
      a_l[i] = *(const u16x8*)&sAl[afo[i]];
      b_h[i] = *(const u16x8*)&sBh[bfo[i]];
      b_l[i] = *(const u16x8*)&sBl[bfo[i]];
    }
#pragma unroll
    for (int mt = 0; mt < 4; ++mt)
#pragma unroll
      for (int nt = 0; nt < 4; ++nt) {
        acc[mt][nt] = mfma16(a_h[mt], b_h[nt], acc[mt][nt]);
        acc[mt][nt] = mfma16(a_l[mt], b_h[nt], acc[mt][nt]);
        acc[mt][nt] = mfma16(a_h[mt], b_l[nt], acc[mt][nt]);
      }
  }

  if (!rec) {
#pragma unroll
    for (int mt = 0; mt < 4; ++mt) {
      int mr = m0 + wm * 64 + mt * 16 + l4 * 4;
#pragma unroll
      for (int nt = 0; nt < 4; ++nt) {
        int nc = n0 + wn * 64 + nt * 16 + l15;
        float bv = bias[nc];
#pragma unroll
        for (int r = 0; r < 4; ++r)
          C[(size_t)(mr + r) * N + nc] = acc[mt][nt][r] + bv;
      }
    }
  } else {
#pragma unroll
    for (int mt = 0; mt < 4; ++mt) {
      int mr = m0 + wm * 64 + mt * 16 + l4 * 4;
#pragma unroll
      for (int nt = 0; nt < 4; ++nt) {
        int nc = n0 + wn * 64 + nt * 16 + l15;
        float bv = bias[nc];
        int unit = nc & 1023;
        int ublk = unit >> 3;
        int uu = unit & 7;
        int gate = nc >> 10;
#pragma unroll
        for (int r = 0; r < 4; ++r) {
          int m = mr + r;
          int tq = (rec == 1) ? (m & 63) : (m >> 6);
          int bq = (rec == 1) ? (m >> 6) : (m & 63);
          size_t idx = ((size_t)(ublk * 64 + tq) * 4 + gate) * 512 + bq * 8 + uu;
          C[idx] = acc[mt][nt][r] + bv;
        }
      }
    }
  }
}

// ---------- l1 pointwise on one chunk ----------
__global__ void k_pw(const float* __restrict__ xg, u16* __restrict__ hhi,
                     u16* __restrict__ hlo) {
  int idx = blockIdx.x * 256 + threadIdx.x;  // MC*H_ threads
  int r = idx >> 10, j = idx & 1023;
  const float* g = xg + (size_t)r * G4;
  float cc = sigmoidf_(g[j]) * tanhf(g[2048 + j]);
  float h = sigmoidf_(g[3072 + j]) * tanhf(cc);
  u16 hh = f2bf(h);
  hhi[idx] = hh;
  hlo[idx] = f2bf(h - bf2f(hh));
}

// ---------- dual-instance persistent recurrent LSTM dispatch ----------
// 256 blocks x 512 threads, 1 block/CU (~147KB LDS).
//   blk>>7 = half (A: rec-layer0 chunk c; B: rec-layer1 chunk c-1), blk&127 = ublk.
// v4: NO block-wide barriers in the round loop. Wave pair {2m,2m+1} is a closed
// producer/consumer set for its sg rows [16m,16m+16): matmul wave (mt=m,kh) writes
// plane kh; pointwise waves 2m,2m+1 (batches [8wv,8wv+8)) read both planes.
// Pair-local LDS handshakes replace __syncthreads:
//   sWr[wv] = t+1 after sg slice written (lgkmcnt(0) first);
//   sRd[wv] = t+1 after pointwise consumed sg (reads retired);
//   writer spins on partner sRd >= t, reader spins on partner sWr >= t+1.
// Global h-exchange keeps the proven protocol: sc0sc1 ring stores, own-wave vmcnt
// drain, per-producer-wave dense flags [half][wave][ublk], relaxed agent polls.
__global__ __launch_bounds__(512, 2) void k_recd(
    const float* __restrict__ xgA, const float* __restrict__ xgB,
    const u16* __restrict__ WAhi, const u16* __restrict__ WAlo,
    const u16* __restrict__ WBhi, const u16* __restrict__ WBlo,
    u16* __restrict__ rAH, u16* __restrict__ rAL,   // half-A h ring [64][64][1024]
    u16* __restrict__ rBH, u16* __restrict__ rBL,   // half-B h ring
    u16* __restrict__ cAH, u16* __restrict__ cAL,   // chunk-carry h [64][1024]
    u16* __restrict__ cBH, u16* __restrict__ cBL,
    float* __restrict__ cbA, float* __restrict__ cbB,  // c state [64][1024]
    float* __restrict__ hfB,                        // [64][1024] or null (half B)
    u32* __restrict__ flags)                        // NFLG dense flags
{
  __shared__ __attribute__((aligned(16))) u16 sW[66048];  // [2][32][1032]  129 KB
  __shared__ float sg[2][64][34];                          // [kh][m][col]   17 KB
  __shared__ int sSync[256];   // sWr at [wv*16], sRd at [128 + wv*16]
  __shared__ int sDead;

  const int tid = threadIdx.x;
  const int lane = tid & 63, wv = tid >> 6;
  const int l15 = lane & 15, l4 = lane >> 4;
  const int L = blockIdx.x >> 7, ublk = blockIdx.x & 127;
  const int u0 = ublk * 8;

  const float* xg = L ? xgB : xgA;
  if (!xg) return;
  const u16* Whi = L ? WBhi : WAhi;
  const u16* Wlo = L ? WBlo : WAlo;
  u16* ringH = L ? rBH : rAH;
  u16* ringL = L ? rBL : rAL;
  u16* carryH = L ? cBH : cAH;
  u16* carryL = L ? cBL : cAL;
  float* cbp = L ? cbB : cbA;
  float* hfinal = L ? hfB : nullptr;
  u32* flg = flags + L * 1024;

  volatile int* vSync = (volatile int*)sSync;
  if (tid == 0) sDead = 0;
  for (int i = tid; i < 256; i += 512) sSync[i] = 0;

  // ---- one-time: Whh slice (32 gate-cols x 1024, hi+lo) into LDS ----
  for (int ci = tid; ci < 8192; ci += 512) {
    int plane = ci >> 12, rem = ci & 4095;
    int n = rem >> 7, ch = rem & 127;
    int wrow = (n >> 3) * 1024 + u0 + (n & 7);
    const u16* src = (plane ? Wlo : Whi) + (size_t)wrow * 1024 + ch * 8;
    *(u16x8*)&sW[plane * 33024 + n * 1032 + ch * 8] = *(const u16x8*)src;
  }
  __syncthreads();

  const int mt = wv >> 1, kh = wv & 1;        // m-tile (16 batches), k-half (512)
  const int aoff = (mt * 16 + l15) * 1024 + kh * 512 + l4 * 8;
  const int bof0 = l15 * 1032 + kh * 512 + l4 * 8;
  const int bof1 = (16 + l15) * 1032 + kh * 512 + l4 * 8;

  // pair handshake slots
  const int iWrOwn = wv * 16, iWrPar = (wv ^ 1) * 16;
  const int iRdOwn = 128 + wv * 16, iRdPar = 128 + (wv ^ 1) * 16;

  // poll set: producer waves {2mt, 2mt+1} over blocks {kh*64 + lane}
  const u32* f0a = flg + (2 * mt) * 128 + kh * 64 + lane;
  const u32* f0b = flg + (2 * mt + 1) * 128 + kh * 64 + lane;
  u32* fown = flg + wv * 128 + ublk;

  // pointwise cell: batch pb (0..63), unit uu (0..7)
  const int pb = tid >> 3, uu = tid & 7;
  const int cidx = pb * 1024 + u0 + uu;
  float c = cbp[cidx];
  const float* xgb = xg + (size_t)ublk * 131072 + pb * 8 + uu;

  for (int t = 0; t < TC; ++t) {
    // ---- xg prefetch (produced by an earlier dispatch; safe pre-wait) ----
    float px0, px1, px2, px3;
    {
      const float* xa = xgb + (size_t)t * 2048;
      asm volatile("global_load_dword %0, %1, off" : "=v"(px0) : "v"(xa));
      asm volatile("global_load_dword %0, %1, off" : "=v"(px1) : "v"(xa + 512));
      asm volatile("global_load_dword %0, %1, off" : "=v"(px2) : "v"(xa + 1024));
      asm volatile("global_load_dword %0, %1, off" : "=v"(px3) : "v"(xa + 1536));
    }

    // ---- per-wave poll of own-half producer waves ----
    if (t > 0 && *(volatile int*)&sDead == 0) {
      int guard = 0;
      for (;;) {
        u32 a = __hip_atomic_load(f0a, __ATOMIC_RELAXED, __HIP_MEMORY_SCOPE_AGENT);
        u32 b = __hip_atomic_load(f0b, __ATOMIC_RELAXED, __HIP_MEMORY_SCOPE_AGENT);
        if (a >= (u32)t && b >= (u32)t) break;
        if (++guard > (1 << 17)) { if (lane == 0) sDead = 1; break; }
        __builtin_amdgcn_s_sleep(1);
      }
    }

    // ---- recurrent matmul over this wave's k-half ----
    const u16* oah = (t ? ringH + (size_t)(t - 1) * 65536 : carryH) + aoff;
    const u16* oal = (t ? ringL + (size_t)(t - 1) * 65536 : carryL) + aoff;
    f32x4 aq[2][2] = {};   // [nt][kc parity]
#pragma unroll
    for (int kc = 0; kc < 16; ++kc) {
      const int ko = kc * 32;
      u16x8 oh = *(const u16x8*)(oah + ko);
      u16x8 ol = *(const u16x8*)(oal + ko);
      u16x8 b0h = *(const u16x8*)&sW[bof0 + ko];
      u16x8 b0l = *(const u16x8*)&sW[33024 + bof0 + ko];
      u16x8 b1h = *(const u16x8*)&sW[bof1 + ko];
      u16x8 b1l = *(const u16x8*)&sW[33024 + bof1 + ko];
      aq[0][kc & 1] = mfma16(oh, b0h, aq[0][kc & 1]);
      aq[0][kc & 1] = mfma16(ol, b0h, aq[0][kc & 1]);
      aq[0][kc & 1] = mfma16(oh, b0l, aq[0][kc & 1]);
      aq[1][kc & 1] = mfma16(oh, b1h, aq[1][kc & 1]);
      aq[1][kc & 1] = mfma16(ol, b1h, aq[1][kc & 1]);
      aq[1][kc & 1] = mfma16(oh, b1l, aq[1][kc & 1]);
    }
    f32x4 A0 = aq[0][0] + aq[0][1];
    f32x4 A1 = aq[1][0] + aq[1][1];

    // ---- pair handshake: wait partner consumed sg of round t-1 ----
    if (t > 0) {
      while (vSync[iRdPar] < t) __builtin_amdgcn_s_sleep(1);
    }
#pragma unroll
    for (int r4 = 0; r4 < 4; ++r4) {
      int m = mt * 16 + l4 * 4 + r4;
      sg[kh][m][l15] = A0[r4];
      sg[kh][m][16 + l15] = A1[r4];
    }
    lgkm0();                       // sg slice retired in LDS
    if (lane == 0) vSync[iWrOwn] = t + 1;
    while (vSync[iWrPar] < t + 1) __builtin_amdgcn_s_sleep(1);

    // ---- pointwise on all 512 threads (reads pair-local sg rows) ----
    float g0 = sg[0][pb][uu] + sg[1][pb][uu];
    float g1 = sg[0][pb][8 + uu] + sg[1][pb][8 + uu];
    float g2 = sg[0][pb][16 + uu] + sg[1][pb][16 + uu];
    float g3 = sg[0][pb][24 + uu] + sg[1][pb][24 + uu];
    lgkm0();                       // sg reads retired
    if (lane == 0) vSync[iRdOwn] = t + 1;
    waitcnt0();  // px ready
    g0 += px0; g1 += px1; g2 += px2; g3 += px3;
    c = sigmoidf_(g1) * c + sigmoidf_(g0) * tanhf(g2);
    float h = sigmoidf_(g3) * tanhf(c);
    u32 hiu = (u32)f2bf(h);
    u32 lou = (u32)f2bf(h - bf2f((u16)hiu));
    u32 hiN = __shfl_down(hiu, 1);
    u32 loN = __shfl_down(lou, 1);
    if ((tid & 1) == 0) {
      size_t re = (size_t)t * 65536 + (size_t)pb * 1024 + u0 + uu;
      store4_cc(ringH + re, hiu | (hiN << 16));
      store4_cc(ringL + re, lou | (loN << 16));
      if (t == TC - 1) {
        store4_cc(carryH + cidx, hiu | (hiN << 16));
        store4_cc(carryL + cidx, lou | (loN << 16));
      }
    }
    if (hfinal && t == TC - 1) hfinal[cidx] = h;

    // ---- drain own wave's stores, raise own flag ----
    waitcnt0();
    if (lane == 0) store4_cc_u32(fown, (u32)(t + 1));
  }

  cbp[cidx] = c;
}

// ---------- MLP (fp32 vector) ----------
__global__ void k_fc(const float* __restrict__ in, const float* __restrict__ W,
                     const float* __restrict__ bias, float* __restrict__ out,
                     int K, int N, int relu) {
  int b = blockIdx.x;
  int n = blockIdx.y * 256 + threadIdx.x;
  if (n >= N) return;
  const float4* wr = (const float4*)(W + (size_t)n * K);
  const float4* xr = (const float4*)(in + (size_t)b * K);
  float s = 0.f;
  for (int k = 0; k < K / 4; ++k) {
    float4 w = wr[k], x = xr[k];
    s += w.x * x.x + w.y * x.y + w.z * x.z + w.w * x.w;
  }
  s += bias[n];
  if (relu) s = fmaxf(s, 0.f);
  out[(size_t)b * N + n] = s;
}

__global__ void k_out(const float* __restrict__ z, const float* __restrict__ W3,
                      const float* __restrict__ b3, float* __restrict__ outp) {
  int b = blockIdx.x;
  int lane = threadIdx.x;  // 64
  const float4* wr = (const float4*)W3;
  const float4* xr = (const float4*)(z + b * 512);
  float s = 0.f;
  for (int k = lane; k < 128; k += 64) {
    float4 w = wr[k], x = xr[k];
    s += w.x * x.x + w.y * x.y + w.z * x.z + w.w * x.w;
  }
  for (int off = 32; off; off >>= 1) s += __shfl_down(s, off);
  if (lane == 0) outp[b] = s + b3[0];
}

// ---------- launch ----------
extern "C" void kernel_launch(void* const* d_in, const int* in_sizes, int n_in,
                              void* d_out, int out_size, void* d_ws, size_t ws_size,
                              hipStream_t stream) {
  (void)in_sizes; (void)n_in; (void)out_size; (void)ws_size;
  const float* xx  = (const float*)d_in[0];
  const float* W10 = (const float*)d_in[1];
  const float* b10i = (const float*)d_in[2];
  const float* b10h = (const float*)d_in[3];
  const float* W11 = (const float*)d_in[4];
  const float* b11i = (const float*)d_in[5];
  const float* b11h = (const float*)d_in[6];
  const float* W20 = (const float*)d_in[7];
  const float* Wh0 = (const float*)d_in[8];
  const float* b20i = (const float*)d_in[9];
  const float* b20h = (const float*)d_in[10];
  const float* W21 = (const float*)d_in[11];
  const float* Wh1 = (const float*)d_in[12];
  const float* b21i = (const float*)d_in[13];
  const float* b21h = (const float*)d_in[14];
  const float* mW1 = (const float*)d_in[15];
  const float* mb1 = (const float*)d_in[16];
  const float* mW2 = (const float*)d_in[17];
  const float* mb2 = (const float*)d_in[18];
  const float* mW3 = (const float*)d_in[19];
  const float* mb3 = (const float*)d_in[20];

  char* ws = (char*)d_ws;
  size_t o = 0;
  float* XG0 = (float*)(ws + o); o += (size_t)MC * G4 * 4;           // 64 MiB (l1 xg + l2-0 gates)
  float* XG1 = (float*)(ws + o); o += (size_t)MC * G4 * 4;           // 64 MiB (l2-1 gates)
  u16* Aah = (u16*)(ws + o); o += (size_t)MC * H_ * 2;               // l1 ping / h1 ring
  u16* Aal = (u16*)(ws + o); o += (size_t)MC * H_ * 2;
  u16* Abh = (u16*)(ws + o); o += (size_t)MC * H_ * 2;               // l1 pong / h0 ring
  u16* Abl = (u16*)(ws + o); o += (size_t)MC * H_ * 2;
  u16* XXh = (u16*)(ws + o); o += (size_t)MC * D_ * 2;
  u16* XXl = (u16*)(ws + o); o += (size_t)MC * D_ * 2;
  u16* W10h = (u16*)(ws + o); o += (size_t)G4 * D_ * 2;
  u16* W10l = (u16*)(ws + o); o += (size_t)G4 * D_ * 2;
  u16* W11h = (u16*)(ws + o); o += (size_t)G4 * H_ * 2;
  u16* W11l = (u16*)(ws + o); o += (size_t)G4 * H_ * 2;
  u16* W20h = (u16*)(ws + o); o += (size_t)G4 * H_ * 2;
  u16* W20l = (u16*)(ws + o); o += (size_t)G4 * H_ * 2;
  u16* Wh0h = (u16*)(ws + o); o += (size_t)G4 * H_ * 2;
  u16* Wh0l = (u16*)(ws + o); o += (size_t)G4 * H_ * 2;
  u16* W21h = (u16*)(ws + o); o += (size_t)G4 * H_ * 2;
  u16* W21l = (u16*)(ws + o); o += (size_t)G4 * H_ * 2;
  u16* Wh1h = (u16*)(ws + o); o += (size_t)G4 * H_ * 2;
  u16* Wh1l = (u16*)(ws + o); o += (size_t)G4 * H_ * 2;
  float* bs0 = (float*)(ws + o); o += G4 * 4;
  float* bs1 = (float*)(ws + o); o += G4 * 4;
  float* bs2 = (float*)(ws + o); o += G4 * 4;
  float* bs3 = (float*)(ws + o); o += G4 * 4;
  // state region (zeroed once per launch, contiguous)
  char* ST = ws + o;
  u16* h00H = (u16*)(ws + o); o += B_ * H_ * 2;
  u16* h00L = (u16*)(ws + o); o += B_ * H_ * 2;
  u16* h01H = (u16*)(ws + o); o += B_ * H_ * 2;
  u16* h01L = (u16*)(ws + o); o += B_ * H_ * 2;
  float* cb0 = (float*)(ws + o); o += B_ * H_ * 4;
  float* cb1 = (float*)(ws + o); o += B_ * H_ * 4;
  u32* FLG = (u32*)(ws + o); o += (NCHUNK + 1) * NFLG * 4;
  size_t stBytes = (size_t)((ws + o) - ST);
  float* FH = (float*)(ws + o); o += B_ * H_ * 4;
  float* Z1 = (float*)(ws + o); o += B_ * H_ * 4;
  float* Z2 = (float*)(ws + o); o += B_ * 512 * 4;

  // rings alias the l1 ping/pong buffers (lifetimes verified: ring0=Ab is
  // consumed by the XG1 GEMM before pw rewrites Ab; ring1=Aa is dead before
  // pw rewrites Aa).
  u16 *r0H = Abh, *r0L = Abl, *r1H = Aah, *r1L = Aal;

  // --- one-time weight/bias prep ---
  k_split<<<(G4 * D_ / 4 + 255) / 256, 256, 0, stream>>>(W10, W10h, W10l, G4 * D_ / 4);
  k_split<<<(G4 * H_ / 4 + 255) / 256, 256, 0, stream>>>(W11, W11h, W11l, G4 * H_ / 4);
  k_split<<<(G4 * H_ / 4 + 255) / 256, 256, 0, stream>>>(W20, W20h, W20l, G4 * H_ / 4);
  k_split<<<(G4 * H_ / 4 + 255) / 256, 256, 0, stream>>>(Wh0, Wh0h, Wh0l, G4 * H_ / 4);
  k_split<<<(G4 * H_ / 4 + 255) / 256, 256, 0, stream>>>(W21, W21h, W21l, G4 * H_ / 4);
  k_split<<<(G4 * H_ / 4 + 255) / 256, 256, 0, stream>>>(Wh1, Wh1h, Wh1l, G4 * H_ / 4);
  k_addvec<<<16, 256, 0, stream>>>(b10i, b10h, bs0, G4);
  k_addvec<<<16, 256, 0, stream>>>(b11i, b11h, bs1, G4);
  k_addvec<<<16, 256, 0, stream>>>(b20i, b20h, bs2, G4);
  k_addvec<<<16, 256, 0, stream>>>(b21i, b21h, bs3, G4);
  hipMemsetAsync(ST, 0, stBytes, stream);

  dim3 gg(MC / 128, G4 / 128);
  const int pwBlocks = MC * H_ / 256;

  for (int c = 0; c < NCHUNK; ++c) {
    int t0 = c * TC;
    k_split_x<<<(MC * (D_ / 4) + 255) / 256, 256, 0, stream>>>(xx, XXh, XXl, t0);
    // l1 layer 0
    k_gemm3<<<gg, 256, 0, stream>>>(XXh, XXl, W10h, W10l, bs0, XG0, MC, G4, D_, 0);
    k_pw<<<pwBlocks, 256, 0, stream>>>(XG0, Aah, Aal);
    // l1 layer 1
    k_gemm3<<<gg, 256, 0, stream>>>(Aah, Aal, W11h, W11l, bs1, XG0, MC, G4, H_, 0);
    k_pw<<<pwBlocks, 256, 0, stream>>>(XG0, Abh, Abl);
    // l2-0 gates (rec layout, A rows b-major = l1 output)
    k_gemm3<<<gg, 256, 0, stream>>>(Abh, Abl, W20h, W20l, bs2, XG0, MC, G4, H_, 1);
    // dual dispatch: rec0(c) [half A] || rec1(c-1) [half B]
    k_recd<<<256, 512, 0, stream>>>(XG0, (c > 0) ? XG1 : nullptr,
                                    Wh0h, Wh0l, Wh1h, Wh1l,
                                    r0H, r0L, r1H, r1L,
                                    h00H, h00L, h01H, h01L, cb0, cb1,
                                    nullptr, FLG + c * NFLG);
    // l2-1 gates from the fresh h0 ring (rec layout, A rows t-major)
    k_gemm3<<<gg, 256, 0, stream>>>(r0H, r0L, W21h, W21l, bs3, XG1, MC, G4, H_, 2);
  }
  // tail: rec1(NCHUNK-1) alone [half B], writes FH
  k_recd<<<256, 512, 0, stream>>>(nullptr, XG1,
                                  Wh0h, Wh0l, Wh1h, Wh1l,
                                  r0H, r0L, r1H, r1L,
                                  h00H, h00L, h01H, h01L, cb0, cb1,
                                  FH, FLG + NCHUNK * NFLG);

  // MLP
  k_fc<<<dim3(B_, 4), 256, 0, stream>>>(FH, mW1, mb1, Z1, H_, H_, 1);
  k_fc<<<dim3(B_, 2), 256, 0, stream>>>(Z1, mW2, mb2, Z2, H_, 512, 1);
  k_out<<<B_, 64, 0, stream>>>(Z2, mW3, mb3, (float*)d_out);
}

// Round 5
// 4729.086 us; speedup vs baseline: 1.1741x; 1.1741x over previous
//
#include <hip/hip_runtime.h>

typedef unsigned short u16;
typedef unsigned int u32;
typedef u16 u16x8 __attribute__((ext_vector_type(8)));
typedef u16 u16x4 __attribute__((ext_vector_type(4)));
typedef __bf16 bf16x8 __attribute__((ext_vector_type(8)));
typedef float f32x4 __attribute__((ext_vector_type(4)));

#define B_ 64
#define T_ 256
#define D_ 256
#define H_ 1024
#define G4 4096
#define TC 64            // timesteps per chunk
#define MC 4096          // rows per chunk (B_*TC)
#define NCHUNK 4
#define NFLG 2048        // flags per dispatch: [2 half][8 wave][128 ublk]

// ---------- helpers ----------
__device__ __forceinline__ u16 f2bf(float x) {
  u32 u = __builtin_bit_cast(u32, x);
  u += 0x7fffu + ((u >> 16) & 1u);
  return (u16)(u >> 16);
}
__device__ __forceinline__ float bf2f(u16 h) {
  u32 u = ((u32)h) << 16;
  return __builtin_bit_cast(float, u);
}
__device__ __forceinline__ float sigmoidf_(float x) { return 1.f / (1.f + __expf(-x)); }

__device__ __forceinline__ f32x4 mfma16(u16x8 a, u16x8 b, f32x4 c) {
  return __builtin_amdgcn_mfma_f32_16x16x32_bf16(
      __builtin_bit_cast(bf16x8, a), __builtin_bit_cast(bf16x8, b), c, 0, 0, 0);
}

__device__ __forceinline__ void gl2lds16(const u16* g, u16* l) {
  __builtin_amdgcn_global_load_lds(
      (const __attribute__((address_space(1))) u32*)(const void*)g,
      (__attribute__((address_space(3))) u32*)(void*)l, 16, 0, 0);
}

// device-coherent (write-through past non-coherent L2) 4B store
__device__ __forceinline__ void store4_cc(u16* p, u32 v) {
  asm volatile("global_store_dword %0, %1, off sc0 sc1" :: "v"(p), "v"(v) : "memory");
}
__device__ __forceinline__ void store4_cc_u32(u32* p, u32 v) {
  asm volatile("global_store_dword %0, %1, off sc0 sc1" :: "v"(p), "v"(v) : "memory");
}
__device__ __forceinline__ void waitcnt0() {
  asm volatile("s_waitcnt vmcnt(0)" ::: "memory");
}

// ---------- split fp32 -> (hi, lo) bf16 planes ----------
__global__ void k_split(const float* __restrict__ src, u16* __restrict__ hi,
                        u16* __restrict__ lo, int n4) {
  int i = blockIdx.x * 256 + threadIdx.x;
  if (i >= n4) return;
  const float4* s4 = (const float4*)src;
  float4 v = s4[i];
  u16 h0 = f2bf(v.x), h1 = f2bf(v.y), h2 = f2bf(v.z), h3 = f2bf(v.w);
  u16x4 hv = {h0, h1, h2, h3};
  u16x4 lv = {f2bf(v.x - bf2f(h0)), f2bf(v.y - bf2f(h1)),
              f2bf(v.z - bf2f(h2)), f2bf(v.w - bf2f(h3))};
  *(u16x4*)(hi + 4 * (size_t)i) = hv;
  *(u16x4*)(lo + 4 * (size_t)i) = lv;
}

// gather one time-chunk of xx ([B,T,D] -> [B*TC, D]) and split planes
__global__ void k_split_x(const float* __restrict__ xx, u16* __restrict__ hi,
                          u16* __restrict__ lo, int t0) {
  int i = blockIdx.x * 256 + threadIdx.x;   // over MC * D_/4
  if (i >= MC * (D_ / 4)) return;
  int row = i >> 6, c4 = i & 63;
  int b = row >> 6, tc = row & 63;
  const float4* s4 = (const float4*)xx;
  float4 v = s4[(size_t)(b * T_ + t0 + tc) * (D_ / 4) + c4];
  u16 h0 = f2bf(v.x), h1 = f2bf(v.y), h2 = f2bf(v.z), h3 = f2bf(v.w);
  u16x4 hv = {h0, h1, h2, h3};
  u16x4 lv = {f2bf(v.x - bf2f(h0)), f2bf(v.y - bf2f(h1)),
              f2bf(v.z - bf2f(h2)), f2bf(v.w - bf2f(h3))};
  *(u16x4*)(hi + 4 * (size_t)i) = hv;
  *(u16x4*)(lo + 4 * (size_t)i) = lv;
}

__global__ void k_addvec(const float* __restrict__ a, const float* __restrict__ b,
                         float* __restrict__ o, int n) {
  int i = blockIdx.x * 256 + threadIdx.x;
  if (i < n) o[i] = a[i] + b[i];
}

// ---------- split-precision GEMM: C[M,N] = A[M,K] * B[N,K]^T + bias (fp32 out) ----
// v5: 2-phase double-buffered staging (T3-min): issue next tile's global_load_lds
// BEFORE computing the current tile; ONE barrier per K-step (its implicit
// vmcnt(0)/lgkmcnt(0) drain lands after the stage latency hid under 48 MFMAs).
// rec=0: standard C[m][n].
// rec=1/2: recurrent xg layout: idx = ((ublk*64 + t)*4 + gate)*512 + b*8 + uu
//   with unit=n&1023, ublk=unit>>3, uu=unit&7, gate=n>>10.
//   rec=1: A rows b-major (b=m>>6, t=m&63)  [l1 output]
//   rec=2: A rows t-major (t=m>>6, b=m&63)  [h ring]
__global__ __launch_bounds__(256, 2) void k_gemm3(
    const u16* __restrict__ Ah, const u16* __restrict__ Al,
    const u16* __restrict__ Bh, const u16* __restrict__ Bl,
    const float* __restrict__ bias, float* __restrict__ C,
    int M, int N, int K, int rec)
{
  __shared__ __attribute__((aligned(16))) u16 sAh[2][4096];
  __shared__ __attribute__((aligned(16))) u16 sAl[2][4096];
  __shared__ __attribute__((aligned(16))) u16 sBh[2][4096];
  __shared__ __attribute__((aligned(16))) u16 sBl[2][4096];

  const int tid = threadIdx.x;
  const int lane = tid & 63;
  const int wv = tid >> 6;
  const int wm = wv & 1, wn = wv >> 1;
  const int m0 = blockIdx.x * 128;
  const int n0 = blockIdx.y * 128;

  const int r0 = tid >> 2;
  const int kg = (tid & 3) ^ (r0 & 3);
  const size_t aoff0 = (size_t)(m0 + r0) * K + kg * 8;
  const size_t aoff1 = (size_t)(m0 + r0 + 64) * K + kg * 8;
  const size_t boff0 = (size_t)(n0 + r0) * K + kg * 8;
  const size_t boff1 = (size_t)(n0 + r0 + 64) * K + kg * 8;
  const int lb0 = wv * 512;
  const int lb1 = 2048 + wv * 512;

  const int l15 = lane & 15, l4 = lane >> 4;
  int afo[4], bfo[4];
#pragma unroll
  for (int mt = 0; mt < 4; ++mt) {
    int r = wm * 64 + mt * 16 + l15;
    afo[mt] = (r * 4 + (l4 ^ (r & 3))) * 8;
  }
#pragma unroll
  for (int nt = 0; nt < 4; ++nt) {
    int r = wn * 64 + nt * 16 + l15;
    bfo[nt] = (r * 4 + (l4 ^ (r & 3))) * 8;
  }

#define STAGE_G(bi, kk) do { \
    gl2lds16(Ah + aoff0 + (kk), &sAh[bi][lb0]); \
    gl2lds16(Ah + aoff1 + (kk), &sAh[bi][lb1]); \
    gl2lds16(Al + aoff0 + (kk), &sAl[bi][lb0]); \
    gl2lds16(Al + aoff1 + (kk), &sAl[bi][lb1]); \
    gl2lds16(Bh + boff0 + (kk), &sBh[bi][lb0]); \
    gl2lds16(Bh + boff1 + (kk), &sBh[bi][lb1]); \
    gl2lds16(Bl + boff0 + (kk), &sBl[bi][lb0]); \
    gl2lds16(Bl + boff1 + (kk), &sBl[bi][lb1]); \
  } while (0)

  f32x4 acc[4][4] = {};

  // prologue: stage tile 0 into buffer 0
  STAGE_G(0, 0);
  __syncthreads();          // drains vmcnt -> buf0 ready

  int cur = 0;
  for (int k0 = 0; k0 < K; k0 += 32) {
    if (k0 + 32 < K) STAGE_G(cur ^ 1, k0 + 32);   // prefetch next tile

    u16x8 a_h[4], a_l[4], b_h[4], b_l[4];
#pragma unroll
    for (int i = 0; i < 4; ++i) {
      a_h[i] = *(const u16x8*)&sAh[cur][afo[i]];
      a_l[i] = *(const u16x8*)&sAl[cur][afo[i]];
      b_h[i] = *(const u16x8*)&sBh[cur][bfo[i]];
      b_l[i] = *(const u16x8*)&sBl[cur][bfo[i]];
    }
#pragma unroll
    for (int mt = 0; mt < 4; ++mt)
#pragma unroll
      for (int nt = 0; nt < 4; ++nt) {
        acc[mt][nt] = mfma16(a_h[mt], b_h[nt], acc[mt][nt]);
        acc[mt][nt] = mfma16(a_l[mt], b_h[nt], acc[mt][nt]);
        acc[mt][nt] = mfma16(a_h[mt], b_l[nt], acc[mt][nt]);
      }

    __syncthreads();        // implicit vmcnt(0)+lgkmcnt(0): next buf staged,
    cur ^= 1;               // current buf fully consumed by all waves
  }
#undef STAGE_G

  if (!rec) {
#pragma unroll
    for (int mt = 0; mt < 4; ++mt) {
      int mr = m0 + wm * 64 + mt * 16 + l4 * 4;
#pragma unroll
      for (int nt = 0; nt < 4; ++nt) {
        int nc = n0 + wn * 64 + nt * 16 + l15;
        float bv = bias[nc];
#pragma unroll
        for (int r = 0; r < 4; ++r)
          C[(size_t)(mr + r) * N + nc] = acc[mt][nt][r] + bv;
      }
    }
  } else {
#pragma unroll
    for (int mt = 0; mt < 4; ++mt) {
      int mr = m0 + wm * 64 + mt * 16 + l4 * 4;
#pragma unroll
      for (int nt = 0; nt < 4; ++nt) {
        int nc = n0 + wn * 64 + nt * 16 + l15;
        float bv = bias[nc];
        int unit = nc & 1023;
        int ublk = unit >> 3;
        int uu = unit & 7;
        int gate = nc >> 10;
#pragma unroll
        for (int r = 0; r < 4; ++r) {
          int m = mr + r;
          int tq = (rec == 1) ? (m & 63) : (m >> 6);
          int bq = (rec == 1) ? (m >> 6) : (m & 63);
          size_t idx = ((size_t)(ublk * 64 + tq) * 4 + gate) * 512 + bq * 8 + uu;
          C[idx] = acc[mt][nt][r] + bv;
        }
      }
    }
  }
}

// ---------- l1 pointwise on one chunk ----------
__global__ void k_pw(const float* __restrict__ xg, u16* __restrict__ hhi,
                     u16* __restrict__ hlo) {
  int idx = blockIdx.x * 256 + threadIdx.x;  // MC*H_ threads
  int r = idx >> 10, j = idx & 1023;
  const float* g = xg + (size_t)r * G4;
  float cc = sigmoidf_(g[j]) * tanhf(g[2048 + j]);
  float h = sigmoidf_(g[3072 + j]) * tanhf(cc);
  u16 hh = f2bf(h);
  hhi[idx] = hh;
  hlo[idx] = f2bf(h - bf2f(hh));
}

// ---------- dual-instance persistent recurrent LSTM dispatch ----------
// (reverted to the proven round-3 structure: 2 block barriers per round +
// per-producer-wave dense flags; the pair-handshake variant regressed.)
// 256 blocks x 512 threads, 1 block/CU (146.5KB LDS).
//   blk>>7 = half (A: rec-layer0 chunk c; B: rec-layer1 chunk c-1), blk&127 = ublk.
__global__ __launch_bounds__(512, 2) void k_recd(
    const float* __restrict__ xgA, const float* __restrict__ xgB,
    const u16* __restrict__ WAhi, const u16* __restrict__ WAlo,
    const u16* __restrict__ WBhi, const u16* __restrict__ WBlo,
    u16* __restrict__ rAH, u16* __restrict__ rAL,   // half-A h ring [64][64][1024]
    u16* __restrict__ rBH, u16* __restrict__ rBL,   // half-B h ring
    u16* __restrict__ cAH, u16* __restrict__ cAL,   // chunk-carry h [64][1024]
    u16* __restrict__ cBH, u16* __restrict__ cBL,
    float* __restrict__ cbA, float* __restrict__ cbB,  // c state [64][1024]
    float* __restrict__ hfB,                        // [64][1024] or null (half B)
    u32* __restrict__ flags)                        // NFLG dense flags
{
  __shared__ __attribute__((aligned(16))) u16 sW[66048];  // [2][32][1032]  129 KB
  __shared__ float sg[2][64][34];                          // [kh][m][col]   17 KB
  __shared__ int sDead;

  const int tid = threadIdx.x;
  const int lane = tid & 63, wv = tid >> 6;
  const int l15 = lane & 15, l4 = lane >> 4;
  const int L = blockIdx.x >> 7, ublk = blockIdx.x & 127;
  const int u0 = ublk * 8;

  const float* xg = L ? xgB : xgA;
  if (!xg) return;
  const u16* Whi = L ? WBhi : WAhi;
  const u16* Wlo = L ? WBlo : WAlo;
  u16* ringH = L ? rBH : rAH;
  u16* ringL = L ? rBL : rAL;
  u16* carryH = L ? cBH : cAH;
  u16* carryL = L ? cBL : cAL;
  float* cbp = L ? cbB : cbA;
  float* hfinal = L ? hfB : nullptr;
  u32* flg = flags + L * 1024;

  if (tid == 0) sDead = 0;

  // ---- one-time: Whh slice (32 gate-cols x 1024, hi+lo) into LDS ----
  for (int ci = tid; ci < 8192; ci += 512) {
    int plane = ci >> 12, rem = ci & 4095;
    int n = rem >> 7, ch = rem & 127;
    int wrow = (n >> 3) * 1024 + u0 + (n & 7);
    const u16* src = (plane ? Wlo : Whi) + (size_t)wrow * 1024 + ch * 8;
    *(u16x8*)&sW[plane * 33024 + n * 1032 + ch * 8] = *(const u16x8*)src;
  }
  __syncthreads();

  const int mt = wv >> 1, kh = wv & 1;        // m-tile (16 batches), k-half (512)
  const int aoff = (mt * 16 + l15) * 1024 + kh * 512 + l4 * 8;
  const int bof0 = l15 * 1032 + kh * 512 + l4 * 8;
  const int bof1 = (16 + l15) * 1032 + kh * 512 + l4 * 8;

  // poll set: producer waves {2mt, 2mt+1} over blocks {kh*64 + lane}
  const u32* f0a = flg + (2 * mt) * 128 + kh * 64 + lane;
  const u32* f0b = flg + (2 * mt + 1) * 128 + kh * 64 + lane;
  u32* fown = flg + wv * 128 + ublk;

  // pointwise cell: batch pb (0..63), unit uu (0..7)
  const int pb = tid >> 3, uu = tid & 7;
  const int cidx = pb * 1024 + u0 + uu;
  float c = cbp[cidx];
  const float* xgb = xg + (size_t)ublk * 131072 + pb * 8 + uu;

  for (int t = 0; t < TC; ++t) {
    // ---- xg prefetch (produced by an earlier dispatch; safe pre-wait) ----
    float px0, px1, px2, px3;
    {
      const float* xa = xgb + (size_t)t * 2048;
      asm volatile("global_load_dword %0, %1, off" : "=v"(px0) : "v"(xa));
      asm volatile("global_load_dword %0, %1, off" : "=v"(px1) : "v"(xa + 512));
      asm volatile("global_load_dword %0, %1, off" : "=v"(px2) : "v"(xa + 1024));
      asm volatile("global_load_dword %0, %1, off" : "=v"(px3) : "v"(xa + 1536));
    }

    // ---- per-wave poll of own-half producer waves ----
    if (t > 0 && *(volatile int*)&sDead == 0) {
      int guard = 0;
      for (;;) {
        u32 a = __hip_atomic_load(f0a, __ATOMIC_RELAXED, __HIP_MEMORY_SCOPE_AGENT);
        u32 b = __hip_atomic_load(f0b, __ATOMIC_RELAXED, __HIP_MEMORY_SCOPE_AGENT);
        if (a >= (u32)t && b >= (u32)t) break;
        if (++guard > (1 << 17)) { if (lane == 0) sDead = 1; break; }
        __builtin_amdgcn_s_sleep(1);
      }
    }

    // ---- recurrent matmul over this wave's k-half ----
    const u16* oah = (t ? ringH + (size_t)(t - 1) * 65536 : carryH) + aoff;
    const u16* oal = (t ? ringL + (size_t)(t - 1) * 65536 : carryL) + aoff;
    f32x4 aq[2][2] = {};   // [nt][kc parity]
#pragma unroll
    for (int kc = 0; kc < 16; ++kc) {
      const int ko = kc * 32;
      u16x8 oh = *(const u16x8*)(oah + ko);
      u16x8 ol = *(const u16x8*)(oal + ko);
      u16x8 b0h = *(const u16x8*)&sW[bof0 + ko];
      u16x8 b0l = *(const u16x8*)&sW[33024 + bof0 + ko];
      u16x8 b1h = *(const u16x8*)&sW[bof1 + ko];
      u16x8 b1l = *(const u16x8*)&sW[33024 + bof1 + ko];
      aq[0][kc & 1] = mfma16(oh, b0h, aq[0][kc & 1]);
      aq[0][kc & 1] = mfma16(ol, b0h, aq[0][kc & 1]);
      aq[0][kc & 1] = mfma16(oh, b0l, aq[0][kc & 1]);
      aq[1][kc & 1] = mfma16(oh, b1h, aq[1][kc & 1]);
      aq[1][kc & 1] = mfma16(ol, b1h, aq[1][kc & 1]);
      aq[1][kc & 1] = mfma16(oh, b1l, aq[1][kc & 1]);
    }
    f32x4 A0 = aq[0][0] + aq[0][1];
    f32x4 A1 = aq[1][0] + aq[1][1];

    __syncthreads();   // prev round's sg fully consumed
#pragma unroll
    for (int r4 = 0; r4 < 4; ++r4) {
      int m = mt * 16 + l4 * 4 + r4;
      sg[kh][m][l15] = A0[r4];
      sg[kh][m][16 + l15] = A1[r4];
    }
    __syncthreads();   // sg ready

    // ---- pointwise on all 512 threads ----
    float g0 = sg[0][pb][uu] + sg[1][pb][uu];
    float g1 = sg[0][pb][8 + uu] + sg[1][pb][8 + uu];
    float g2 = sg[0][pb][16 + uu] + sg[1][pb][16 + uu];
    float g3 = sg[0][pb][24 + uu] + sg[1][pb][24 + uu];
    waitcnt0();  // px ready
    g0 += px0; g1 += px1; g2 += px2; g3 += px3;
    c = sigmoidf_(g1) * c + sigmoidf_(g0) * tanhf(g2);
    float h = sigmoidf_(g3) * tanhf(c);
    u32 hiu = (u32)f2bf(h);
    u32 lou = (u32)f2bf(h - bf2f((u16)hiu));
    u32 hiN = __shfl_down(hiu, 1);
    u32 loN = __shfl_down(lou, 1);
    if ((tid & 1) == 0) {
      size_t re = (size_t)t * 65536 + (size_t)pb * 1024 + u0 + uu;
      store4_cc(ringH + re, hiu | (hiN << 16));
      store4_cc(ringL + re, lou | (loN << 16));
      if (t == TC - 1) {
        store4_cc(carryH + cidx, hiu | (hiN << 16));
        store4_cc(carryL + cidx, lou | (loN << 16));
      }
    }
    if (hfinal && t == TC - 1) hfinal[cidx] = h;

    // ---- drain own wave's stores, raise own flag ----
    waitcnt0();
    if (lane == 0) store4_cc_u32(fown, (u32)(t + 1));
  }

  cbp[cidx] = c;
}

// ---------- MLP (fp32 vector) ----------
__global__ void k_fc(const float* __restrict__ in, const float* __restrict__ W,
                     const float* __restrict__ bias, float* __restrict__ out,
                     int K, int N, int relu) {
  int b = blockIdx.x;
  int n = blockIdx.y * 256 + threadIdx.x;
  if (n >= N) return;
  const float4* wr = (const float4*)(W + (size_t)n * K);
  const float4* xr = (const float4*)(in + (size_t)b * K);
  float s = 0.f;
  for (int k = 0; k < K / 4; ++k) {
    float4 w = wr[k], x = xr[k];
    s += w.x * x.x + w.y * x.y + w.z * x.z + w.w * x.w;
  }
  s += bias[n];
  if (relu) s = fmaxf(s, 0.f);
  out[(size_t)b * N + n] = s;
}

__global__ void k_out(const float* __restrict__ z, const float* __restrict__ W3,
                      const float* __restrict__ b3, float* __restrict__ outp) {
  int b = blockIdx.x;
  int lane = threadIdx.x;  // 64
  const float4* wr = (const float4*)W3;
  const float4* xr = (const float4*)(z + b * 512);
  float s = 0.f;
  for (int k = lane; k < 128; k += 64) {
    float4 w = wr[k], x = xr[k];
    s += w.x * x.x + w.y * x.y + w.z * x.z + w.w * x.w;
  }
  for (int off = 32; off; off >>= 1) s += __shfl_down(s, off);
  if (lane == 0) outp[b] = s + b3[0];
}

// ---------- launch ----------
extern "C" void kernel_launch(void* const* d_in, const int* in_sizes, int n_in,
                              void* d_out, int out_size, void* d_ws, size_t ws_size,
                              hipStream_t stream) {
  (void)in_sizes; (void)n_in; (void)out_size; (void)ws_size;
  const float* xx  = (const float*)d_in[0];
  const float* W10 = (const float*)d_in[1];
  const float* b10i = (const float*)d_in[2];
  const float* b10h = (const float*)d_in[3];
  const float* W11 = (const float*)d_in[4];
  const float* b11i = (const float*)d_in[5];
  const float* b11h = (const float*)d_in[6];
  const float* W20 = (const float*)d_in[7];
  const float* Wh0 = (const float*)d_in[8];
  const float* b20i = (const float*)d_in[9];
  const float* b20h = (const float*)d_in[10];
  const float* W21 = (const float*)d_in[11];
  const float* Wh1 = (const float*)d_in[12];
  const float* b21i = (const float*)d_in[13];
  const float* b21h = (const float*)d_in[14];
  const float* mW1 = (const float*)d_in[15];
  const float* mb1 = (const float*)d_in[16];
  const float* mW2 = (const float*)d_in[17];
  const float* mb2 = (const float*)d_in[18];
  const float* mW3 = (const float*)d_in[19];
  const float* mb3 = (const float*)d_in[20];

  char* ws = (char*)d_ws;
  size_t o = 0;
  float* XG0 = (float*)(ws + o); o += (size_t)MC * G4 * 4;           // 64 MiB (l1 xg + l2-0 gates)
  float* XG1 = (float*)(ws + o); o += (size_t)MC * G4 * 4;           // 64 MiB (l2-1 gates)
  u16* Aah = (u16*)(ws + o); o += (size_t)MC * H_ * 2;               // l1 ping / h1 ring
  u16* Aal = (u16*)(ws + o); o += (size_t)MC * H_ * 2;
  u16* Abh = (u16*)(ws + o); o += (size_t)MC * H_ * 2;               // l1 pong / h0 ring
  u16* Abl = (u16*)(ws + o); o += (size_t)MC * H_ * 2;
  u16* XXh = (u16*)(ws + o); o += (size_t)MC * D_ * 2;
  u16* XXl = (u16*)(ws + o); o += (size_t)MC * D_ * 2;
  u16* W10h = (u16*)(ws + o); o += (size_t)G4 * D_ * 2;
  u16* W10l = (u16*)(ws + o); o += (size_t)G4 * D_ * 2;
  u16* W11h = (u16*)(ws + o); o += (size_t)G4 * H_ * 2;
  u16* W11l = (u16*)(ws + o); o += (size_t)G4 * H_ * 2;
  u16* W20h = (u16*)(ws + o); o += (size_t)G4 * H_ * 2;
  u16* W20l = (u16*)(ws + o); o += (size_t)G4 * H_ * 2;
  u16* Wh0h = (u16*)(ws + o); o += (size_t)G4 * H_ * 2;
  u16* Wh0l = (u16*)(ws + o); o += (size_t)G4 * H_ * 2;
  u16* W21h = (u16*)(ws + o); o += (size_t)G4 * H_ * 2;
  u16* W21l = (u16*)(ws + o); o += (size_t)G4 * H_ * 2;
  u16* Wh1h = (u16*)(ws + o); o += (size_t)G4 * H_ * 2;
  u16* Wh1l = (u16*)(ws + o); o += (size_t)G4 * H_ * 2;
  float* bs0 = (float*)(ws + o); o += G4 * 4;
  float* bs1 = (float*)(ws + o); o += G4 * 4;
  float* bs2 = (float*)(ws + o); o += G4 * 4;
  float* bs3 = (float*)(ws + o); o += G4 * 4;
  // state region (zeroed once per launch, contiguous)
  char* ST = ws + o;
  u16* h00H = (u16*)(ws + o); o += B_ * H_ * 2;
  u16* h00L = (u16*)(ws + o); o += B_ * H_ * 2;
  u16* h01H = (u16*)(ws + o); o += B_ * H_ * 2;
  u16* h01L = (u16*)(ws + o); o += B_ * H_ * 2;
  float* cb0 = (float*)(ws + o); o += B_ * H_ * 4;
  float* cb1 = (float*)(ws + o); o += B_ * H_ * 4;
  u32* FLG = (u32*)(ws + o); o += (NCHUNK + 1) * NFLG * 4;
  size_t stBytes = (size_t)((ws + o) - ST);
  float* FH = (float*)(ws + o); o += B_ * H_ * 4;
  float* Z1 = (float*)(ws + o); o += B_ * H_ * 4;
  float* Z2 = (float*)(ws + o); o += B_ * 512 * 4;

  // rings alias the l1 ping/pong buffers (lifetimes verified: ring0=Ab is
  // consumed by the XG1 GEMM before pw rewrites Ab; ring1=Aa is dead before
  // pw rewrites Aa).
  u16 *r0H = Abh, *r0L = Abl, *r1H = Aah, *r1L = Aal;

  // --- one-time weight/bias prep ---
  k_split<<<(G4 * D_ / 4 + 255) / 256, 256, 0, stream>>>(W10, W10h, W10l, G4 * D_ / 4);
  k_split<<<(G4 * H_ / 4 + 255) / 256, 256, 0, stream>>>(W11, W11h, W11l, G4 * H_ / 4);
  k_split<<<(G4 * H_ / 4 + 255) / 256, 256, 0, stream>>>(W20, W20h, W20l, G4 * H_ / 4);
  k_split<<<(G4 * H_ / 4 + 255) / 256, 256, 0, stream>>>(Wh0, Wh0h, Wh0l, G4 * H_ / 4);
  k_split<<<(G4 * H_ / 4 + 255) / 256, 256, 0, stream>>>(W21, W21h, W21l, G4 * H_ / 4);
  k_split<<<(G4 * H_ / 4 + 255) / 256, 256, 0, stream>>>(Wh1, Wh1h, Wh1l, G4 * H_ / 4);
  k_addvec<<<16, 256, 0, stream>>>(b10i, b10h, bs0, G4);
  k_addvec<<<16, 256, 0, stream>>>(b11i, b11h, bs1, G4);
  k_addvec<<<16, 256, 0, stream>>>(b20i, b20h, bs2, G4);
  k_addvec<<<16, 256, 0, stream>>>(b21i, b21h, bs3, G4);
  hipMemsetAsync(ST, 0, stBytes, stream);

  dim3 gg(MC / 128, G4 / 128);
  const int pwBlocks = MC * H_ / 256;

  for (int c = 0; c < NCHUNK; ++c) {
    int t0 = c * TC;
    k_split_x<<<(MC * (D_ / 4) + 255) / 256, 256, 0, stream>>>(xx, XXh, XXl, t0);
    // l1 layer 0
    k_gemm3<<<gg, 256, 0, stream>>>(XXh, XXl, W10h, W10l, bs0, XG0, MC, G4, D_, 0);
    k_pw<<<pwBlocks, 256, 0, stream>>>(XG0, Aah, Aal);
    // l1 layer 1
    k_gemm3<<<gg, 256, 0, stream>>>(Aah, Aal, W11h, W11l, bs1, XG0, MC, G4, H_, 0);
    k_pw<<<pwBlocks, 256, 0, stream>>>(XG0, Abh, Abl);
    // l2-0 gates (rec layout, A rows b-major = l1 output)
    k_gemm3<<<gg, 256, 0, stream>>>(Abh, Abl, W20h, W20l, bs2, XG0, MC, G4, H_, 1);
    // dual dispatch: rec0(c) [half A] || rec1(c-1) [half B]
    k_recd<<<256, 512, 0, stream>>>(XG0, (c > 0) ? XG1 : nullptr,
                                    Wh0h, Wh0l, Wh1h, Wh1l,
                                    r0H, r0L, r1H, r1L,
                                    h00H, h00L, h01H, h01L, cb0, cb1,
                                    nullptr, FLG + c * NFLG);
    // l2-1 gates from the fresh h0 ring (rec layout, A rows t-major)
    k_gemm3<<<gg, 256, 0, stream>>>(r0H, r0L, W21h, W21l, bs3, XG1, MC, G4, H_, 2);
  }
  // tail: rec1(NCHUNK-1) alone [half B], writes FH
  k_recd<<<256, 512, 0, stream>>>(nullptr, XG1,
                                  Wh0h, Wh0l, Wh1h, Wh1l,
                                  r0H, r0L, r1H, r1L,
                                  h00H, h00L, h01H, h01L, cb0, cb1,
                                  FH, FLG + NCHUNK * NFLG);

  // MLP
  k_fc<<<dim3(B_, 4), 256, 0, stream>>>(FH, mW1, mb1, Z1, H_, H_, 1);
  k_fc<<<dim3(B_, 2), 256, 0, stream>>>(Z1, mW2, mb2, Z2, H_, 512, 1);
  k_out<<<B_, 64, 0, stream>>>(Z2, mW3, mb3, (float*)d_out);
}

// Round 6
// 4518.238 us; speedup vs baseline: 1.2289x; 1.0467x over previous
//
#include <hip/hip_runtime.h>

typedef unsigned short u16;
typedef unsigned int u32;
typedef u16 u16x8 __attribute__((ext_vector_type(8)));
typedef u16 u16x4 __attribute__((ext_vector_type(4)));
typedef __bf16 bf16x8 __attribute__((ext_vector_type(8)));
typedef float f32x4 __attribute__((ext_vector_type(4)));

#define B_ 64
#define T_ 256
#define D_ 256
#define H_ 1024
#define G4 4096
#define TC 32            // timesteps per chunk
#define TCSH 5
#define MC 2048          // rows per chunk (B_*TC)
#define NCHUNK 8
#define NFLG 2048        // flags per dispatch: [2 half][8 wave][128 ublk]

// ---------- helpers ----------
__device__ __forceinline__ u16 f2bf(float x) {
  u32 u = __builtin_bit_cast(u32, x);
  u += 0x7fffu + ((u >> 16) & 1u);
  return (u16)(u >> 16);
}
__device__ __forceinline__ float bf2f(u16 h) {
  u32 u = ((u32)h) << 16;
  return __builtin_bit_cast(float, u);
}
__device__ __forceinline__ float sigmoidf_(float x) { return 1.f / (1.f + __expf(-x)); }

__device__ __forceinline__ f32x4 mfma16(u16x8 a, u16x8 b, f32x4 c) {
  return __builtin_amdgcn_mfma_f32_16x16x32_bf16(
      __builtin_bit_cast(bf16x8, a), __builtin_bit_cast(bf16x8, b), c, 0, 0, 0);
}

__device__ __forceinline__ void gl2lds16(const u16* g, u16* l) {
  __builtin_amdgcn_global_load_lds(
      (const __attribute__((address_space(1))) u32*)(const void*)g,
      (__attribute__((address_space(3))) u32*)(void*)l, 16, 0, 0);
}

// device-coherent (write-through past non-coherent L2) 4B store
__device__ __forceinline__ void store4_cc(u16* p, u32 v) {
  asm volatile("global_store_dword %0, %1, off sc0 sc1" :: "v"(p), "v"(v) : "memory");
}
__device__ __forceinline__ void store4_cc_u32(u32* p, u32 v) {
  asm volatile("global_store_dword %0, %1, off sc0 sc1" :: "v"(p), "v"(v) : "memory");
}
__device__ __forceinline__ void waitcnt0() {
  asm volatile("s_waitcnt vmcnt(0)" ::: "memory");
}

// ---------- split fp32 -> (hi, lo) bf16 planes ----------
__global__ void k_split(const float* __restrict__ src, u16* __restrict__ hi,
                        u16* __restrict__ lo, int n4) {
  int i = blockIdx.x * 256 + threadIdx.x;
  if (i >= n4) return;
  const float4* s4 = (const float4*)src;
  float4 v = s4[i];
  u16 h0 = f2bf(v.x), h1 = f2bf(v.y), h2 = f2bf(v.z), h3 = f2bf(v.w);
  u16x4 hv = {h0, h1, h2, h3};
  u16x4 lv = {f2bf(v.x - bf2f(h0)), f2bf(v.y - bf2f(h1)),
              f2bf(v.z - bf2f(h2)), f2bf(v.w - bf2f(h3))};
  *(u16x4*)(hi + 4 * (size_t)i) = hv;
  *(u16x4*)(lo + 4 * (size_t)i) = lv;
}

// permuted split for l1 weights: row g*1024+u -> (u>>4)*64 + g*16 + (u&15).
// s = log2(K/4) (row length in float4).
__global__ void k_splitp(const float* __restrict__ src, u16* __restrict__ hi,
                         u16* __restrict__ lo, int n4, int s) {
  int i = blockIdx.x * 256 + threadIdx.x;
  if (i >= n4) return;
  int row = i >> s, col4 = i & ((1 << s) - 1);
  int g = row >> 10, u = row & 1023;
  int prow = ((u >> 4) << 6) + (g << 4) + (u & 15);
  size_t di = ((size_t)prow << s) | col4;
  const float4* s4 = (const float4*)src;
  float4 v = s4[i];
  u16 h0 = f2bf(v.x), h1 = f2bf(v.y), h2 = f2bf(v.z), h3 = f2bf(v.w);
  u16x4 hv = {h0, h1, h2, h3};
  u16x4 lv = {f2bf(v.x - bf2f(h0)), f2bf(v.y - bf2f(h1)),
              f2bf(v.z - bf2f(h2)), f2bf(v.w - bf2f(h3))};
  *(u16x4*)(hi + 4 * di) = hv;
  *(u16x4*)(lo + 4 * di) = lv;
}

// gather one time-chunk of xx ([B,T,D] -> [B*TC, D]) and split planes
__global__ void k_split_x(const float* __restrict__ xx, u16* __restrict__ hi,
                          u16* __restrict__ lo, int t0) {
  int i = blockIdx.x * 256 + threadIdx.x;   // over MC * D_/4
  if (i >= MC * (D_ / 4)) return;
  int row = i >> 6, c4 = i & 63;
  int b = row >> TCSH, tc = row & (TC - 1);
  const float4* s4 = (const float4*)xx;
  float4 v = s4[(size_t)(b * T_ + t0 + tc) * (D_ / 4) + c4];
  u16 h0 = f2bf(v.x), h1 = f2bf(v.y), h2 = f2bf(v.z), h3 = f2bf(v.w);
  u16x4 hv = {h0, h1, h2, h3};
  u16x4 lv = {f2bf(v.x - bf2f(h0)), f2bf(v.y - bf2f(h1)),
              f2bf(v.z - bf2f(h2)), f2bf(v.w - bf2f(h3))};
  *(u16x4*)(hi + 4 * (size_t)i) = hv;
  *(u16x4*)(lo + 4 * (size_t)i) = lv;
}

__global__ void k_addvec(const float* __restrict__ a, const float* __restrict__ b,
                         float* __restrict__ o, int n) {
  int i = blockIdx.x * 256 + threadIdx.x;
  if (i < n) o[i] = a[i] + b[i];
}

// permuted bias add for l1 layers
__global__ void k_addp(const float* __restrict__ a, const float* __restrict__ b,
                       float* __restrict__ o) {
  int i = blockIdx.x * 256 + threadIdx.x;
  if (i >= G4) return;
  int g = i >> 10, u = i & 1023;
  int prow = ((u >> 4) << 6) + (g << 4) + (u & 15);
  o[prow] = a[i] + b[i];
}

// ---------- split-precision GEMM: C[M,N] = A[M,K] * B[N,K]^T + bias ----------
// 2-phase double-buffered staging (prefetch next K-tile before computing current).
// rec=0: standard fp32 C[m][n].
// rec=1/2: recurrent xg layout: idx = ((ublk*TC + t)*4 + gate)*512 + b*8 + uu
//   with unit=n&1023, ublk=unit>>3, uu=unit&7, gate=n>>10.
//   rec=1: A rows b-major (b=m>>TCSH, t=m&(TC-1))  [l1 output]
//   rec=2: A rows t-major (t=m>>6, b=m&63)         [h ring]
// rec=3: fused l1 epilogue. B/bias are PERMUTED (k_splitp/k_addp): wave wn's
//   64-col group = units [cb>>6*16, +16) x gates 0..3 with nt==gate; each thread
//   holds all 4 gates of (row, unit) in acc[mt][0..3][r]; applies the l1 cell
//   (c=0 single step) and writes h hi/lo planes directly (Hh/Hl).
__global__ __launch_bounds__(256, 2) void k_gemm3(
    const u16* __restrict__ Ah, const u16* __restrict__ Al,
    const u16* __restrict__ Bh, const u16* __restrict__ Bl,
    const float* __restrict__ bias, float* __restrict__ C,
    u16* __restrict__ Hh, u16* __restrict__ Hl,
    int M, int N, int K, int rec)
{
  __shared__ __attribute__((aligned(16))) u16 sAh[2][4096];
  __shared__ __attribute__((aligned(16))) u16 sAl[2][4096];
  __shared__ __attribute__((aligned(16))) u16 sBh[2][4096];
  __shared__ __attribute__((aligned(16))) u16 sBl[2][4096];

  const int tid = threadIdx.x;
  const int lane = tid & 63;
  const int wv = tid >> 6;
  const int wm = wv & 1, wn = wv >> 1;
  const int m0 = blockIdx.x * 128;
  const int n0 = blockIdx.y * 128;

  const int r0 = tid >> 2;
  const int kg = (tid & 3) ^ (r0 & 3);
  const size_t aoff0 = (size_t)(m0 + r0) * K + kg * 8;
  const size_t aoff1 = (size_t)(m0 + r0 + 64) * K + kg * 8;
  const size_t boff0 = (size_t)(n0 + r0) * K + kg * 8;
  const size_t boff1 = (size_t)(n0 + r0 + 64) * K + kg * 8;
  const int lb0 = wv * 512;
  const int lb1 = 2048 + wv * 512;

  const int l15 = lane & 15, l4 = lane >> 4;
  int afo[4], bfo[4];
#pragma unroll
  for (int mt = 0; mt < 4; ++mt) {
    int r = wm * 64 + mt * 16 + l15;
    afo[mt] = (r * 4 + (l4 ^ (r & 3))) * 8;
  }
#pragma unroll
  for (int nt = 0; nt < 4; ++nt) {
    int r = wn * 64 + nt * 16 + l15;
    bfo[nt] = (r * 4 + (l4 ^ (r & 3))) * 8;
  }

#define STAGE_G(bi, kk) do { \
    gl2lds16(Ah + aoff0 + (kk), &sAh[bi][lb0]); \
    gl2lds16(Ah + aoff1 + (kk), &sAh[bi][lb1]); \
    gl2lds16(Al + aoff0 + (kk), &sAl[bi][lb0]); \
    gl2lds16(Al + aoff1 + (kk), &sAl[bi][lb1]); \
    gl2lds16(Bh + boff0 + (kk), &sBh[bi][lb0]); \
    gl2lds16(Bh + boff1 + (kk), &sBh[bi][lb1]); \
    gl2lds16(Bl + boff0 + (kk), &sBl[bi][lb0]); \
    gl2lds16(Bl + boff1 + (kk), &sBl[bi][lb1]); \
  } while (0)

  f32x4 acc[4][4] = {};

  STAGE_G(0, 0);
  __syncthreads();

  int cur = 0;
  for (int k0 = 0; k0 < K; k0 += 32) {
    if (k0 + 32 < K) STAGE_G(cur ^ 1, k0 + 32);

    u16x8 a_h[4], a_l[4], b_h[4], b_l[4];
#pragma unroll
    for (int i = 0; i < 4; ++i) {
      a_h[i] = *(const u16x8*)&sAh[cur][afo[i]];
      a_l[i] = *(const u16x8*)&sAl[cur][afo[i]];
      b_h[i] = *(const u16x8*)&sBh[cur][bfo[i]];
      b_l[i] = *(const u16x8*)&sBl[cur][bfo[i]];
    }
#pragma unroll
    for (int mt = 0; mt < 4; ++mt)
#pragma unroll
      for (int nt = 0; nt < 4; ++nt) {
        acc[mt][nt] = mfma16(a_h[mt], b_h[nt], acc[mt][nt]);
        acc[mt][nt] = mfma16(a_l[mt], b_h[nt], acc[mt][nt]);
        acc[mt][nt] = mfma16(a_h[mt], b_l[nt], acc[mt][nt]);
      }

    __syncthreads();
    cur ^= 1;
  }
#undef STAGE_G

  if (rec == 0) {
#pragma unroll
    for (int mt = 0; mt < 4; ++mt) {
      int mr = m0 + wm * 64 + mt * 16 + l4 * 4;
#pragma unroll
      for (int nt = 0; nt < 4; ++nt) {
        int nc = n0 + wn * 64 + nt * 16 + l15;
        float bv = bias[nc];
#pragma unroll
        for (int r = 0; r < 4; ++r)
          C[(size_t)(mr + r) * N + nc] = acc[mt][nt][r] + bv;
      }
    }
  } else if (rec == 3) {
    const int cb = n0 + wn * 64;
    const int ub = (cb >> 6) * 16 + l15;       // unit for this thread
    const float bvi = bias[cb + l15];          // gate i (cols +0)
    const float bvg = bias[cb + 32 + l15];     // gate g (cols +32)
    const float bvo = bias[cb + 48 + l15];     // gate o (cols +48)
#pragma unroll
    for (int mt = 0; mt < 4; ++mt) {
      int mr = m0 + wm * 64 + mt * 16 + l4 * 4;
#pragma unroll
      for (int r = 0; r < 4; ++r) {
        float gi = acc[mt][0][r] + bvi;
        float gg = acc[mt][2][r] + bvg;
        float go = acc[mt][3][r] + bvo;
        float cc2 = sigmoidf_(gi) * tanhf(gg);
        float h = sigmoidf_(go) * tanhf(cc2);
        u16 hh = f2bf(h);
        size_t oi = (size_t)(mr + r) * 1024 + ub;
        Hh[oi] = hh;
        Hl[oi] = f2bf(h - bf2f(hh));
      }
    }
  } else {
#pragma unroll
    for (int mt = 0; mt < 4; ++mt) {
      int mr = m0 + wm * 64 + mt * 16 + l4 * 4;
#pragma unroll
      for (int nt = 0; nt < 4; ++nt) {
        int nc = n0 + wn * 64 + nt * 16 + l15;
        float bv = bias[nc];
        int unit = nc & 1023;
        int ublk = unit >> 3;
        int uu = unit & 7;
        int gate = nc >> 10;
#pragma unroll
        for (int r = 0; r < 4; ++r) {
          int m = mr + r;
          int tq = (rec == 1) ? (m & (TC - 1)) : (m >> 6);
          int bq = (rec == 1) ? (m >> TCSH) : (m & 63);
          size_t idx = ((size_t)(ublk * TC + tq) * 4 + gate) * 512 + bq * 8 + uu;
          C[idx] = acc[mt][nt][r] + bv;
        }
      }
    }
  }
}

// ---------- dual-instance persistent recurrent LSTM dispatch ----------
// (proven round-3 structure: 2 block barriers per round + per-producer-wave
// dense flags.) 256 blocks x 512 threads, 1 block/CU (146.5KB LDS).
//   blk>>7 = half (A: rec-layer0 chunk c; B: rec-layer1 chunk c-1), blk&127 = ublk.
__global__ __launch_bounds__(512, 2) void k_recd(
    const float* __restrict__ xgA, const float* __restrict__ xgB,
    const u16* __restrict__ WAhi, const u16* __restrict__ WAlo,
    const u16* __restrict__ WBhi, const u16* __restrict__ WBlo,
    u16* __restrict__ rAH, u16* __restrict__ rAL,   // half-A h ring [TC][64][1024]
    u16* __restrict__ rBH, u16* __restrict__ rBL,   // half-B h ring
    u16* __restrict__ cAH, u16* __restrict__ cAL,   // chunk-carry h [64][1024]
    u16* __restrict__ cBH, u16* __restrict__ cBL,
    float* __restrict__ cbA, float* __restrict__ cbB,  // c state [64][1024]
    float* __restrict__ hfB,                        // [64][1024] or null (half B)
    u32* __restrict__ flags)                        // NFLG dense flags
{
  __shared__ __attribute__((aligned(16))) u16 sW[66048];  // [2][32][1032]  129 KB
  __shared__ float sg[2][64][34];                          // [kh][m][col]   17 KB
  __shared__ int sDead;

  const int tid = threadIdx.x;
  const int lane = tid & 63, wv = tid >> 6;
  const int l15 = lane & 15, l4 = lane >> 4;
  const int L = blockIdx.x >> 7, ublk = blockIdx.x & 127;
  const int u0 = ublk * 8;

  const float* xg = L ? xgB : xgA;
  if (!xg) return;
  const u16* Whi = L ? WBhi : WAhi;
  const u16* Wlo = L ? WBlo : WAlo;
  u16* ringH = L ? rBH : rAH;
  u16* ringL = L ? rBL : rAL;
  u16* carryH = L ? cBH : cAH;
  u16* carryL = L ? cBL : cAL;
  float* cbp = L ? cbB : cbA;
  float* hfinal = L ? hfB : nullptr;
  u32* flg = flags + L * 1024;

  if (tid == 0) sDead = 0;

  // ---- one-time: Whh slice (32 gate-cols x 1024, hi+lo) into LDS ----
  for (int ci = tid; ci < 8192; ci += 512) {
    int plane = ci >> 12, rem = ci & 4095;
    int n = rem >> 7, ch = rem & 127;
    int wrow = (n >> 3) * 1024 + u0 + (n & 7);
    const u16* src = (plane ? Wlo : Whi) + (size_t)wrow * 1024 + ch * 8;
    *(u16x8*)&sW[plane * 33024 + n * 1032 + ch * 8] = *(const u16x8*)src;
  }
  __syncthreads();

  const int mt = wv >> 1, kh = wv & 1;        // m-tile (16 batches), k-half (512)
  const int aoff = (mt * 16 + l15) * 1024 + kh * 512 + l4 * 8;
  const int bof0 = l15 * 1032 + kh * 512 + l4 * 8;
  const int bof1 = (16 + l15) * 1032 + kh * 512 + l4 * 8;

  // poll set: producer waves {2mt, 2mt+1} over blocks {kh*64 + lane}
  const u32* f0a = flg + (2 * mt) * 128 + kh * 64 + lane;
  const u32* f0b = flg + (2 * mt + 1) * 128 + kh * 64 + lane;
  u32* fown = flg + wv * 128 + ublk;

  // pointwise cell: batch pb (0..63), unit uu (0..7)
  const int pb = tid >> 3, uu = tid & 7;
  const int cidx = pb * 1024 + u0 + uu;
  float c = cbp[cidx];
  const float* xgb = xg + (size_t)ublk * (TC * 2048) + pb * 8 + uu;

  for (int t = 0; t < TC; ++t) {
    // ---- xg prefetch (produced by an earlier dispatch; safe pre-wait) ----
    float px0, px1, px2, px3;
    {
      const float* xa = xgb + (size_t)t * 2048;
      asm volatile("global_load_dword %0, %1, off" : "=v"(px0) : "v"(xa));
      asm volatile("global_load_dword %0, %1, off" : "=v"(px1) : "v"(xa + 512));
      asm volatile("global_load_dword %0, %1, off" : "=v"(px2) : "v"(xa + 1024));
      asm volatile("global_load_dword %0, %1, off" : "=v"(px3) : "v"(xa + 1536));
    }

    // ---- per-wave poll of own-half producer waves ----
    if (t > 0 && *(volatile int*)&sDead == 0) {
      int guard = 0;
      for (;;) {
        u32 a = __hip_atomic_load(f0a, __ATOMIC_RELAXED, __HIP_MEMORY_SCOPE_AGENT);
        u32 b = __hip_atomic_load(f0b, __ATOMIC_RELAXED, __HIP_MEMORY_SCOPE_AGENT);
        if (a >= (u32)t && b >= (u32)t) break;
        if (++guard > (1 << 17)) { if (lane == 0) sDead = 1; break; }
        __builtin_amdgcn_s_sleep(1);
      }
    }

    // ---- recurrent matmul over this wave's k-half ----
    const u16* oah = (t ? ringH + (size_t)(t - 1) * 65536 : carryH) + aoff;
    const u16* oal = (t ? ringL + (size_t)(t - 1) * 65536 : carryL) + aoff;
    f32x4 aq[2][2] = {};   // [nt][kc parity]
#pragma unroll
    for (int kc = 0; kc < 16; ++kc) {
      const int ko = kc * 32;
      u16x8 oh = *(const u16x8*)(oah + ko);
      u16x8 ol = *(const u16x8*)(oal + ko);
      u16x8 b0h = *(const u16x8*)&sW[bof0 + ko];
      u16x8 b0l = *(const u16x8*)&sW[33024 + bof0 + ko];
      u16x8 b1h = *(const u16x8*)&sW[bof1 + ko];
      u16x8 b1l = *(const u16x8*)&sW[33024 + bof1 + ko];
      aq[0][kc & 1] = mfma16(oh, b0h, aq[0][kc & 1]);
      aq[0][kc & 1] = mfma16(ol, b0h, aq[0][kc & 1]);
      aq[0][kc & 1] = mfma16(oh, b0l, aq[0][kc & 1]);
      aq[1][kc & 1] = mfma16(oh, b1h, aq[1][kc & 1]);
      aq[1][kc & 1] = mfma16(ol, b1h, aq[1][kc & 1]);
      aq[1][kc & 1] = mfma16(oh, b1l, aq[1][kc & 1]);
    }
    f32x4 A0 = aq[0][0] + aq[0][1];
    f32x4 A1 = aq[1][0] + aq[1][1];

    __syncthreads();   // prev round's sg fully consumed
#pragma unroll
    for (int r4 = 0; r4 < 4; ++r4) {
      int m = mt * 16 + l4 * 4 + r4;
      sg[kh][m][l15] = A0[r4];
      sg[kh][m][16 + l15] = A1[r4];
    }
    __syncthreads();   // sg ready

    // ---- pointwise on all 512 threads ----
    float g0 = sg[0][pb][uu] + sg[1][pb][uu];
    float g1 = sg[0][pb][8 + uu] + sg[1][pb][8 + uu];
    float g2 = sg[0][pb][16 + uu] + sg[1][pb][16 + uu];
    float g3 = sg[0][pb][24 + uu] + sg[1][pb][24 + uu];
    waitcnt0();  // px ready
    g0 += px0; g1 += px1; g2 += px2; g3 += px3;
    c = sigmoidf_(g1) * c + sigmoidf_(g0) * tanhf(g2);
    float h = sigmoidf_(g3) * tanhf(c);
    u32 hiu = (u32)f2bf(h);
    u32 lou = (u32)f2bf(h - bf2f((u16)hiu));
    u32 hiN = __shfl_down(hiu, 1);
    u32 loN = __shfl_down(lou, 1);
    if ((tid & 1) == 0) {
      size_t re = (size_t)t * 65536 + (size_t)pb * 1024 + u0 + uu;
      store4_cc(ringH + re, hiu | (hiN << 16));
      store4_cc(ringL + re, lou | (loN << 16));
      if (t == TC - 1) {
        store4_cc(carryH + cidx, hiu | (hiN << 16));
        store4_cc(carryL + cidx, lou | (loN << 16));
      }
    }
    if (hfinal && t == TC - 1) hfinal[cidx] = h;

    // ---- drain own wave's stores, raise own flag ----
    waitcnt0();
    if (lane == 0) store4_cc_u32(fown, (u32)(t + 1));
  }

  cbp[cidx] = c;
}

// ---------- MLP (fp32 vector) ----------
__global__ void k_fc(const float* __restrict__ in, const float* __restrict__ W,
                     const float* __restrict__ bias, float* __restrict__ out,
                     int K, int N, int relu) {
  int b = blockIdx.x;
  int n = blockIdx.y * 256 + threadIdx.x;
  if (n >= N) return;
  const float4* wr = (const float4*)(W + (size_t)n * K);
  const float4* xr = (const float4*)(in + (size_t)b * K);
  float s = 0.f;
  for (int k = 0; k < K / 4; ++k) {
    float4 w = wr[k], x = xr[k];
    s += w.x * x.x + w.y * x.y + w.z * x.z + w.w * x.w;
  }
  s += bias[n];
  if (relu) s = fmaxf(s, 0.f);
  out[(size_t)b * N + n] = s;
}

__global__ void k_out(const float* __restrict__ z, const float* __restrict__ W3,
                      const float* __restrict__ b3, float* __restrict__ outp) {
  int b = blockIdx.x;
  int lane = threadIdx.x;  // 64
  const float4* wr = (const float4*)W3;
  const float4* xr = (const float4*)(z + b * 512);
  float s = 0.f;
  for (int k = lane; k < 128; k += 64) {
    float4 w = wr[k], x = xr[k];
    s += w.x * x.x + w.y * x.y + w.z * x.z + w.w * x.w;
  }
  for (int off = 32; off; off >>= 1) s += __shfl_down(s, off);
  if (lane == 0) outp[b] = s + b3[0];
}

// ---------- launch ----------
extern "C" void kernel_launch(void* const* d_in, const int* in_sizes, int n_in,
                              void* d_out, int out_size, void* d_ws, size_t ws_size,
                              hipStream_t stream) {
  (void)in_sizes; (void)n_in; (void)out_size; (void)ws_size;
  const float* xx  = (const float*)d_in[0];
  const float* W10 = (const float*)d_in[1];
  const float* b10i = (const float*)d_in[2];
  const float* b10h = (const float*)d_in[3];
  const float* W11 = (const float*)d_in[4];
  const float* b11i = (const float*)d_in[5];
  const float* b11h = (const float*)d_in[6];
  const float* W20 = (const float*)d_in[7];
  const float* Wh0 = (const float*)d_in[8];
  const float* b20i = (const float*)d_in[9];
  const float* b20h = (const float*)d_in[10];
  const float* W21 = (const float*)d_in[11];
  const float* Wh1 = (const float*)d_in[12];
  const float* b21i = (const float*)d_in[13];
  const float* b21h = (const float*)d_in[14];
  const float* mW1 = (const float*)d_in[15];
  const float* mb1 = (const float*)d_in[16];
  const float* mW2 = (const float*)d_in[17];
  const float* mb2 = (const float*)d_in[18];
  const float* mW3 = (const float*)d_in[19];
  const float* mb3 = (const float*)d_in[20];

  char* ws = (char*)d_ws;
  size_t o = 0;
  float* XG0 = (float*)(ws + o); o += (size_t)MC * G4 * 4;           // 32 MiB (l2-0 gates)
  float* XG1 = (float*)(ws + o); o += (size_t)MC * G4 * 4;           // 32 MiB (l2-1 gates)
  u16* Aah = (u16*)(ws + o); o += (size_t)MC * H_ * 2;               // l1-0 h / h1 ring
  u16* Aal = (u16*)(ws + o); o += (size_t)MC * H_ * 2;
  u16* Abh = (u16*)(ws + o); o += (size_t)MC * H_ * 2;               // l1-1 h / h0 ring
  u16* Abl = (u16*)(ws + o); o += (size_t)MC * H_ * 2;
  u16* XXh = (u16*)(ws + o); o += (size_t)MC * D_ * 2;
  u16* XXl = (u16*)(ws + o); o += (size_t)MC * D_ * 2;
  u16* W10h = (u16*)(ws + o); o += (size_t)G4 * D_ * 2;
  u16* W10l = (u16*)(ws + o); o += (size_t)G4 * D_ * 2;
  u16* W11h = (u16*)(ws + o); o += (size_t)G4 * H_ * 2;
  u16* W11l = (u16*)(ws + o); o += (size_t)G4 * H_ * 2;
  u16* W20h = (u16*)(ws + o); o += (size_t)G4 * H_ * 2;
  u16* W20l = (u16*)(ws + o); o += (size_t)G4 * H_ * 2;
  u16* Wh0h = (u16*)(ws + o); o += (size_t)G4 * H_ * 2;
  u16* Wh0l = (u16*)(ws + o); o += (size_t)G4 * H_ * 2;
  u16* W21h = (u16*)(ws + o); o += (size_t)G4 * H_ * 2;
  u16* W21l = (u16*)(ws + o); o += (size_t)G4 * H_ * 2;
  u16* Wh1h = (u16*)(ws + o); o += (size_t)G4 * H_ * 2;
  u16* Wh1l = (u16*)(ws + o); o += (size_t)G4 * H_ * 2;
  float* bs0 = (float*)(ws + o); o += G4 * 4;   // permuted (l1)
  float* bs1 = (float*)(ws + o); o += G4 * 4;   // permuted (l1)
  float* bs2 = (float*)(ws + o); o += G4 * 4;
  float* bs3 = (float*)(ws + o); o += G4 * 4;
  // state region (zeroed once per launch, contiguous)
  char* ST = ws + o;
  u16* h00H = (u16*)(ws + o); o += B_ * H_ * 2;
  u16* h00L = (u16*)(ws + o); o += B_ * H_ * 2;
  u16* h01H = (u16*)(ws + o); o += B_ * H_ * 2;
  u16* h01L = (u16*)(ws + o); o += B_ * H_ * 2;
  float* cb0 = (float*)(ws + o); o += B_ * H_ * 4;
  float* cb1 = (float*)(ws + o); o += B_ * H_ * 4;
  u32* FLG = (u32*)(ws + o); o += (NCHUNK + 1) * NFLG * 4;
  size_t stBytes = (size_t)((ws + o) - ST);
  float* FH = (float*)(ws + o); o += B_ * H_ * 4;
  float* Z1 = (float*)(ws + o); o += B_ * H_ * 4;
  float* Z2 = (float*)(ws + o); o += B_ * 512 * 4;

  // rings alias the l1 buffers (lifetimes: ring0=Ab consumed by XG1 GEMM before
  // next chunk's l1-1 GEMM rewrites Ab; ring1=Aa dead before l1-0 rewrites Aa).
  u16 *r0H = Abh, *r0L = Abl, *r1H = Aah, *r1L = Aal;

  // --- one-time weight/bias prep ---
  k_splitp<<<(G4 * D_ / 4 + 255) / 256, 256, 0, stream>>>(W10, W10h, W10l, G4 * D_ / 4, 6);
  k_splitp<<<(G4 * H_ / 4 + 255) / 256, 256, 0, stream>>>(W11, W11h, W11l, G4 * H_ / 4, 8);
  k_split<<<(G4 * H_ / 4 + 255) / 256, 256, 0, stream>>>(W20, W20h, W20l, G4 * H_ / 4);
  k_split<<<(G4 * H_ / 4 + 255) / 256, 256, 0, stream>>>(Wh0, Wh0h, Wh0l, G4 * H_ / 4);
  k_split<<<(G4 * H_ / 4 + 255) / 256, 256, 0, stream>>>(W21, W21h, W21l, G4 * H_ / 4);
  k_split<<<(G4 * H_ / 4 + 255) / 256, 256, 0, stream>>>(Wh1, Wh1h, Wh1l, G4 * H_ / 4);
  k_addp<<<16, 256, 0, stream>>>(b10i, b10h, bs0);
  k_addp<<<16, 256, 0, stream>>>(b11i, b11h, bs1);
  k_addvec<<<16, 256, 0, stream>>>(b20i, b20h, bs2, G4);
  k_addvec<<<16, 256, 0, stream>>>(b21i, b21h, bs3, G4);
  hipMemsetAsync(ST, 0, stBytes, stream);

  dim3 gg(MC / 128, G4 / 128);

  for (int c = 0; c < NCHUNK; ++c) {
    int t0 = c * TC;
    k_split_x<<<(MC * (D_ / 4) + 255) / 256, 256, 0, stream>>>(xx, XXh, XXl, t0);
    // l1 layer 0 (fused pointwise epilogue -> h planes in Aa)
    k_gemm3<<<gg, 256, 0, stream>>>(XXh, XXl, W10h, W10l, bs0, nullptr,
                                    Aah, Aal, MC, G4, D_, 3);
    // l1 layer 1 (fused -> Ab)
    k_gemm3<<<gg, 256, 0, stream>>>(Aah, Aal, W11h, W11l, bs1, nullptr,
                                    Abh, Abl, MC, G4, H_, 3);
    // l2-0 gates (rec layout, A rows b-major = l1 output)
    k_gemm3<<<gg, 256, 0, stream>>>(Abh, Abl, W20h, W20l, bs2, XG0,
                                    nullptr, nullptr, MC, G4, H_, 1);
    // dual dispatch: rec0(c) [half A] || rec1(c-1) [half B]
    k_recd<<<256, 512, 0, stream>>>(XG0, (c > 0) ? XG1 : nullptr,
                                    Wh0h, Wh0l, Wh1h, Wh1l,
                                    r0H, r0L, r1H, r1L,
                                    h00H, h00L, h01H, h01L, cb0, cb1,
                                    nullptr, FLG + c * NFLG);
    // l2-1 gates from the fresh h0 ring (rec layout, A rows t-major)
    k_gemm3<<<gg, 256, 0, stream>>>(r0H, r0L, W21h, W21l, bs3, XG1,
                                    nullptr, nullptr, MC, G4, H_, 2);
  }
  // tail: rec1(NCHUNK-1) alone [half B], writes FH
  k_recd<<<256, 512, 0, stream>>>(nullptr, XG1,
                                  Wh0h, Wh0l, Wh1h, Wh1l,
                                  r0H, r0L, r1H, r1L,
                                  h00H, h00L, h01H, h01L, cb0, cb1,
                                  FH, FLG + NCHUNK * NFLG);

  // MLP
  k_fc<<<dim3(B_, 4), 256, 0, stream>>>(FH, mW1, mb1, Z1, H_, H_, 1);
  k_fc<<<dim3(B_, 2), 256, 0, stream>>>(Z1, mW2, mb2, Z2, H_, 512, 1);
  k_out<<<B_, 64, 0, stream>>>(Z2, mW3, mb3, (float*)d_out);
}

// Round 7
// 4488.905 us; speedup vs baseline: 1.2370x; 1.0065x over previous
//
#include <hip/hip_runtime.h>

typedef unsigned short u16;
typedef unsigned int u32;
typedef u16 u16x8 __attribute__((ext_vector_type(8)));
typedef u16 u16x4 __attribute__((ext_vector_type(4)));
typedef u32 u32x4 __attribute__((ext_vector_type(4)));
typedef __bf16 bf16x8 __attribute__((ext_vector_type(8)));
typedef float f32x4 __attribute__((ext_vector_type(4)));

#define B_ 64
#define T_ 256
#define D_ 256
#define H_ 1024
#define G4 4096
#define TC 32            // timesteps per chunk
#define TCSH 5
#define MC 2048          // rows per chunk (B_*TC)
#define NCHUNK 8
#define NFLG 2048        // flags per dispatch: [2 half][8 wave][128 ublk]

// ---------- helpers ----------
__device__ __forceinline__ u16 f2bf(float x) {
  u32 u = __builtin_bit_cast(u32, x);
  u += 0x7fffu + ((u >> 16) & 1u);
  return (u16)(u >> 16);
}
__device__ __forceinline__ float bf2f(u16 h) {
  u32 u = ((u32)h) << 16;
  return __builtin_bit_cast(float, u);
}
__device__ __forceinline__ float sigmoidf_(float x) { return 1.f / (1.f + __expf(-x)); }

__device__ __forceinline__ f32x4 mfma16(u16x8 a, u16x8 b, f32x4 c) {
  return __builtin_amdgcn_mfma_f32_16x16x32_bf16(
      __builtin_bit_cast(bf16x8, a), __builtin_bit_cast(bf16x8, b), c, 0, 0, 0);
}

__device__ __forceinline__ void gl2lds16(const u16* g, u16* l) {
  __builtin_amdgcn_global_load_lds(
      (const __attribute__((address_space(1))) u32*)(const void*)g,
      (__attribute__((address_space(3))) u32*)(void*)l, 16, 0, 0);
}

// device-coherent (write-through past non-coherent L2) stores
__device__ __forceinline__ void store4_cc(u16* p, u32 v) {
  asm volatile("global_store_dword %0, %1, off sc0 sc1" :: "v"(p), "v"(v) : "memory");
}
__device__ __forceinline__ void store4_cc_u32(u32* p, u32 v) {
  asm volatile("global_store_dword %0, %1, off sc0 sc1" :: "v"(p), "v"(v) : "memory");
}
__device__ __forceinline__ void store16_cc(u16* p, u32 a, u32 b, u32 c, u32 d) {
  u32x4 v = {a, b, c, d};
  asm volatile("global_store_dwordx4 %0, %1, off sc0 sc1" :: "v"(p), "v"(v) : "memory");
}
__device__ __forceinline__ void waitcnt0() {
  asm volatile("s_waitcnt vmcnt(0)" ::: "memory");
}

// ---------- split fp32 -> (hi, lo) bf16 planes ----------
__global__ void k_split(const float* __restrict__ src, u16* __restrict__ hi,
                        u16* __restrict__ lo, int n4) {
  int i = blockIdx.x * 256 + threadIdx.x;
  if (i >= n4) return;
  const float4* s4 = (const float4*)src;
  float4 v = s4[i];
  u16 h0 = f2bf(v.x), h1 = f2bf(v.y), h2 = f2bf(v.z), h3 = f2bf(v.w);
  u16x4 hv = {h0, h1, h2, h3};
  u16x4 lv = {f2bf(v.x - bf2f(h0)), f2bf(v.y - bf2f(h1)),
              f2bf(v.z - bf2f(h2)), f2bf(v.w - bf2f(h3))};
  *(u16x4*)(hi + 4 * (size_t)i) = hv;
  *(u16x4*)(lo + 4 * (size_t)i) = lv;
}

// permuted split for l1 weights: row g*1024+u -> (u>>4)*64 + g*16 + (u&15).
// s = log2(K/4) (row length in float4).
__global__ void k_splitp(const float* __restrict__ src, u16* __restrict__ hi,
                         u16* __restrict__ lo, int n4, int s) {
  int i = blockIdx.x * 256 + threadIdx.x;
  if (i >= n4) return;
  int row = i >> s, col4 = i & ((1 << s) - 1);
  int g = row >> 10, u = row & 1023;
  int prow = ((u >> 4) << 6) + (g << 4) + (u & 15);
  size_t di = ((size_t)prow << s) | col4;
  const float4* s4 = (const float4*)src;
  float4 v = s4[i];
  u16 h0 = f2bf(v.x), h1 = f2bf(v.y), h2 = f2bf(v.z), h3 = f2bf(v.w);
  u16x4 hv = {h0, h1, h2, h3};
  u16x4 lv = {f2bf(v.x - bf2f(h0)), f2bf(v.y - bf2f(h1)),
              f2bf(v.z - bf2f(h2)), f2bf(v.w - bf2f(h3))};
  *(u16x4*)(hi + 4 * di) = hv;
  *(u16x4*)(lo + 4 * di) = lv;
}

// gather one time-chunk of xx ([B,T,D] -> [B*TC, D]) and split planes
__global__ void k_split_x(const float* __restrict__ xx, u16* __restrict__ hi,
                          u16* __restrict__ lo, int t0) {
  int i = blockIdx.x * 256 + threadIdx.x;   // over MC * D_/4
  if (i >= MC * (D_ / 4)) return;
  int row = i >> 6, c4 = i & 63;
  int b = row >> TCSH, tc = row & (TC - 1);
  const float4* s4 = (const float4*)xx;
  float4 v = s4[(size_t)(b * T_ + t0 + tc) * (D_ / 4) + c4];
  u16 h0 = f2bf(v.x), h1 = f2bf(v.y), h2 = f2bf(v.z), h3 = f2bf(v.w);
  u16x4 hv = {h0, h1, h2, h3};
  u16x4 lv = {f2bf(v.x - bf2f(h0)), f2bf(v.y - bf2f(h1)),
              f2bf(v.z - bf2f(h2)), f2bf(v.w - bf2f(h3))};
  *(u16x4*)(hi + 4 * (size_t)i) = hv;
  *(u16x4*)(lo + 4 * (size_t)i) = lv;
}

__global__ void k_addvec(const float* __restrict__ a, const float* __restrict__ b,
                         float* __restrict__ o, int n) {
  int i = blockIdx.x * 256 + threadIdx.x;
  if (i < n) o[i] = a[i] + b[i];
}

// permuted bias add for l1 layers
__global__ void k_addp(const float* __restrict__ a, const float* __restrict__ b,
                       float* __restrict__ o) {
  int i = blockIdx.x * 256 + threadIdx.x;
  if (i >= G4) return;
  int g = i >> 10, u = i & 1023;
  int prow = ((u >> 4) << 6) + (g << 4) + (u & 15);
  o[prow] = a[i] + b[i];
}

// ---------- split-precision GEMM: C[M,N] = A[M,K] * B[N,K]^T + bias ----------
// 2-phase double-buffered staging (prefetch next K-tile before computing current).
// rec=0: standard fp32 C[m][n].
// rec=1/2: recurrent xg layout: idx = ((ublk*TC + t)*4 + gate)*512 + b*8 + uu
//   with unit=n&1023, ublk=unit>>3, uu=unit&7, gate=n>>10.
//   rec=1: A rows b-major (b=m>>TCSH, t=m&(TC-1))  [l1 output]
//   rec=2: A rows t-major (t=m>>6, b=m&63)         [h ring]
// rec=3: fused l1 epilogue. B/bias are PERMUTED (k_splitp/k_addp): wave wn's
//   64-col group = units [cb>>6*16, +16) x gates 0..3 with nt==gate; each thread
//   holds all 4 gates of (row, unit) in acc[mt][0..3][r]; applies the l1 cell
//   (c=0 single step) and writes h hi/lo planes directly (Hh/Hl).
__global__ __launch_bounds__(256, 2) void k_gemm3(
    const u16* __restrict__ Ah, const u16* __restrict__ Al,
    const u16* __restrict__ Bh, const u16* __restrict__ Bl,
    const float* __restrict__ bias, float* __restrict__ C,
    u16* __restrict__ Hh, u16* __restrict__ Hl,
    int M, int N, int K, int rec)
{
  __shared__ __attribute__((aligned(16))) u16 sAh[2][4096];
  __shared__ __attribute__((aligned(16))) u16 sAl[2][4096];
  __shared__ __attribute__((aligned(16))) u16 sBh[2][4096];
  __shared__ __attribute__((aligned(16))) u16 sBl[2][4096];

  const int tid = threadIdx.x;
  const int lane = tid & 63;
  const int wv = tid >> 6;
  const int wm = wv & 1, wn = wv >> 1;
  const int m0 = blockIdx.x * 128;
  const int n0 = blockIdx.y * 128;

  const int r0 = tid >> 2;
  const int kg = (tid & 3) ^ (r0 & 3);
  const size_t aoff0 = (size_t)(m0 + r0) * K + kg * 8;
  const size_t aoff1 = (size_t)(m0 + r0 + 64) * K + kg * 8;
  const size_t boff0 = (size_t)(n0 + r0) * K + kg * 8;
  const size_t boff1 = (size_t)(n0 + r0 + 64) * K + kg * 8;
  const int lb0 = wv * 512;
  const int lb1 = 2048 + wv * 512;

  const int l15 = lane & 15, l4 = lane >> 4;
  int afo[4], bfo[4];
#pragma unroll
  for (int mt = 0; mt < 4; ++mt) {
    int r = wm * 64 + mt * 16 + l15;
    afo[mt] = (r * 4 + (l4 ^ (r & 3))) * 8;
  }
#pragma unroll
  for (int nt = 0; nt < 4; ++nt) {
    int r = wn * 64 + nt * 16 + l15;
    bfo[nt] = (r * 4 + (l4 ^ (r & 3))) * 8;
  }

#define STAGE_G(bi, kk) do { \
    gl2lds16(Ah + aoff0 + (kk), &sAh[bi][lb0]); \
    gl2lds16(Ah + aoff1 + (kk), &sAh[bi][lb1]); \
    gl2lds16(Al + aoff0 + (kk), &sAl[bi][lb0]); \
    gl2lds16(Al + aoff1 + (kk), &sAl[bi][lb1]); \
    gl2lds16(Bh + boff0 + (kk), &sBh[bi][lb0]); \
    gl2lds16(Bh + boff1 + (kk), &sBh[bi][lb1]); \
    gl2lds16(Bl + boff0 + (kk), &sBl[bi][lb0]); \
    gl2lds16(Bl + boff1 + (kk), &sBl[bi][lb1]); \
  } while (0)

  f32x4 acc[4][4] = {};

  STAGE_G(0, 0);
  __syncthreads();

  int cur = 0;
  for (int k0 = 0; k0 < K; k0 += 32) {
    if (k0 + 32 < K) STAGE_G(cur ^ 1, k0 + 32);

    u16x8 a_h[4], a_l[4], b_h[4], b_l[4];
#pragma unroll
    for (int i = 0; i < 4; ++i) {
      a_h[i] = *(const u16x8*)&sAh[cur][afo[i]];
      a_l[i] = *(const u16x8*)&sAl[cur][afo[i]];
      b_h[i] = *(const u16x8*)&sBh[cur][bfo[i]];
      b_l[i] = *(const u16x8*)&sBl[cur][bfo[i]];
    }
#pragma unroll
    for (int mt = 0; mt < 4; ++mt)
#pragma unroll
      for (int nt = 0; nt < 4; ++nt) {
        acc[mt][nt] = mfma16(a_h[mt], b_h[nt], acc[mt][nt]);
        acc[mt][nt] = mfma16(a_l[mt], b_h[nt], acc[mt][nt]);
        acc[mt][nt] = mfma16(a_h[mt], b_l[nt], acc[mt][nt]);
      }

    __syncthreads();
    cur ^= 1;
  }
#undef STAGE_G

  if (rec == 0) {
#pragma unroll
    for (int mt = 0; mt < 4; ++mt) {
      int mr = m0 + wm * 64 + mt * 16 + l4 * 4;
#pragma unroll
      for (int nt = 0; nt < 4; ++nt) {
        int nc = n0 + wn * 64 + nt * 16 + l15;
        float bv = bias[nc];
#pragma unroll
        for (int r = 0; r < 4; ++r)
          C[(size_t)(mr + r) * N + nc] = acc[mt][nt][r] + bv;
      }
    }
  } else if (rec == 3) {
    const int cb = n0 + wn * 64;
    const int ub = (cb >> 6) * 16 + l15;       // unit for this thread
    const float bvi = bias[cb + l15];          // gate i (cols +0)
    const float bvg = bias[cb + 32 + l15];     // gate g (cols +32)
    const float bvo = bias[cb + 48 + l15];     // gate o (cols +48)
#pragma unroll
    for (int mt = 0; mt < 4; ++mt) {
      int mr = m0 + wm * 64 + mt * 16 + l4 * 4;
#pragma unroll
      for (int r = 0; r < 4; ++r) {
        float gi = acc[mt][0][r] + bvi;
        float gg = acc[mt][2][r] + bvg;
        float go = acc[mt][3][r] + bvo;
        float cc2 = sigmoidf_(gi) * tanhf(gg);
        float h = sigmoidf_(go) * tanhf(cc2);
        u16 hh = f2bf(h);
        size_t oi = (size_t)(mr + r) * 1024 + ub;
        Hh[oi] = hh;
        Hl[oi] = f2bf(h - bf2f(hh));
      }
    }
  } else {
#pragma unroll
    for (int mt = 0; mt < 4; ++mt) {
      int mr = m0 + wm * 64 + mt * 16 + l4 * 4;
#pragma unroll
      for (int nt = 0; nt < 4; ++nt) {
        int nc = n0 + wn * 64 + nt * 16 + l15;
        float bv = bias[nc];
        int unit = nc & 1023;
        int ublk = unit >> 3;
        int uu = unit & 7;
        int gate = nc >> 10;
#pragma unroll
        for (int r = 0; r < 4; ++r) {
          int m = mr + r;
          int tq = (rec == 1) ? (m & (TC - 1)) : (m >> 6);
          int bq = (rec == 1) ? (m >> TCSH) : (m & 63);
          size_t idx = ((size_t)(ublk * TC + tq) * 4 + gate) * 512 + bq * 8 + uu;
          C[idx] = acc[mt][nt][r] + bv;
        }
      }
    }
  }
}

// ---------- dual-instance persistent recurrent LSTM dispatch ----------
// (proven round-3 protocol: 2 block barriers per round + per-producer-wave
// dense flags.) 256 blocks x 512 threads, 1 block/CU (146.5KB LDS).
//   blk>>7 = half (A: rec-layer0 chunk c; B: rec-layer1 chunk c-1), blk&127 = ublk.
// v7 micro: (1) Whh prologue staged via global_load_lds (dst = wave-uniform base
// + lane*16, verified); (2) A-fragment loads hoisted into arrays (one burst);
// (3) ring/carry stores consolidated to dwordx4 sc0sc1 (4x fewer stores -> faster
// vmcnt drain before flag raise).
__global__ __launch_bounds__(512, 2) void k_recd(
    const float* __restrict__ xgA, const float* __restrict__ xgB,
    const u16* __restrict__ WAhi, const u16* __restrict__ WAlo,
    const u16* __restrict__ WBhi, const u16* __restrict__ WBlo,
    u16* __restrict__ rAH, u16* __restrict__ rAL,   // half-A h ring [TC][64][1024]
    u16* __restrict__ rBH, u16* __restrict__ rBL,   // half-B h ring
    u16* __restrict__ cAH, u16* __restrict__ cAL,   // chunk-carry h [64][1024]
    u16* __restrict__ cBH, u16* __restrict__ cBL,
    float* __restrict__ cbA, float* __restrict__ cbB,  // c state [64][1024]
    float* __restrict__ hfB,                        // [64][1024] or null (half B)
    u32* __restrict__ flags)                        // NFLG dense flags
{
  __shared__ __attribute__((aligned(16))) u16 sW[66048];  // [2][32][1032]  129 KB
  __shared__ float sg[2][64][34];                          // [kh][m][col]   17 KB
  __shared__ int sDead;

  const int tid = threadIdx.x;
  const int lane = tid & 63, wv = tid >> 6;
  const int l15 = lane & 15, l4 = lane >> 4;
  const int L = blockIdx.x >> 7, ublk = blockIdx.x & 127;
  const int u0 = ublk * 8;

  const float* xg = L ? xgB : xgA;
  if (!xg) return;
  const u16* Whi = L ? WBhi : WAhi;
  const u16* Wlo = L ? WBlo : WAlo;
  u16* ringH = L ? rBH : rAH;
  u16* ringL = L ? rBL : rAL;
  u16* carryH = L ? cBH : cAH;
  u16* carryL = L ? cBL : cAL;
  float* cbp = L ? cbB : cbA;
  float* hfinal = L ? hfB : nullptr;
  u32* flg = flags + L * 1024;

  if (tid == 0) sDead = 0;

  // ---- one-time: Whh slice (32 gate-cols x 1024, hi+lo) into LDS via gl2lds ----
  // ci = tid + k*512: plane = ci>>12, n = (ci&4095)>>7, ch = ci&127.
  // dst byte = plane*66048 + n*2064 + ch*16  (= base + lane*16 within each wave).
  for (int ci = tid; ci < 8192; ci += 512) {
    int plane = ci >> 12, rem = ci & 4095;
    int n = rem >> 7, ch = rem & 127;
    int wrow = (n >> 3) * 1024 + u0 + (n & 7);
    const u16* src = (plane ? Wlo : Whi) + (size_t)wrow * 1024 + ch * 8;
    gl2lds16(src, &sW[plane * 33024 + n * 1032 + ch * 8]);
  }
  __syncthreads();   // drains vmcnt -> sW ready

  const int mt = wv >> 1, kh = wv & 1;        // m-tile (16 batches), k-half (512)
  const int aoff = (mt * 16 + l15) * 1024 + kh * 512 + l4 * 8;
  const int bof0 = l15 * 1032 + kh * 512 + l4 * 8;
  const int bof1 = (16 + l15) * 1032 + kh * 512 + l4 * 8;

  // poll set: producer waves {2mt, 2mt+1} over blocks {kh*64 + lane}
  const u32* f0a = flg + (2 * mt) * 128 + kh * 64 + lane;
  const u32* f0b = flg + (2 * mt + 1) * 128 + kh * 64 + lane;
  u32* fown = flg + wv * 128 + ublk;

  // pointwise cell: batch pb (0..63), unit uu (0..7)
  const int pb = tid >> 3, uu = tid & 7;
  const int cidx = pb * 1024 + u0 + uu;
  float c = cbp[cidx];
  const float* xgb = xg + (size_t)ublk * (TC * 2048) + pb * 8 + uu;

  for (int t = 0; t < TC; ++t) {
    // ---- xg prefetch (produced by an earlier dispatch; safe pre-wait) ----
    float px0, px1, px2, px3;
    {
      const float* xa = xgb + (size_t)t * 2048;
      asm volatile("global_load_dword %0, %1, off" : "=v"(px0) : "v"(xa));
      asm volatile("global_load_dword %0, %1, off" : "=v"(px1) : "v"(xa + 512));
      asm volatile("global_load_dword %0, %1, off" : "=v"(px2) : "v"(xa + 1024));
      asm volatile("global_load_dword %0, %1, off" : "=v"(px3) : "v"(xa + 1536));
    }

    // ---- per-wave poll of own-half producer waves ----
    if (t > 0 && *(volatile int*)&sDead == 0) {
      int guard = 0;
      for (;;) {
        u32 a = __hip_atomic_load(f0a, __ATOMIC_RELAXED, __HIP_MEMORY_SCOPE_AGENT);
        u32 b = __hip_atomic_load(f0b, __ATOMIC_RELAXED, __HIP_MEMORY_SCOPE_AGENT);
        if (a >= (u32)t && b >= (u32)t) break;
        if (++guard > (1 << 17)) { if (lane == 0) sDead = 1; break; }
        __builtin_amdgcn_s_sleep(1);
      }
    }

    // ---- recurrent matmul over this wave's k-half (A-loads hoisted) ----
    const u16* oah = (t ? ringH + (size_t)(t - 1) * 65536 : carryH) + aoff;
    const u16* oal = (t ? ringL + (size_t)(t - 1) * 65536 : carryL) + aoff;
    u16x8 oh[16], ol[16];
#pragma unroll
    for (int kc = 0; kc < 16; ++kc) {
      oh[kc] = *(const u16x8*)(oah + kc * 32);
      ol[kc] = *(const u16x8*)(oal + kc * 32);
    }
    f32x4 aq[2][2] = {};   // [nt][kc parity]
#pragma unroll
    for (int kc = 0; kc < 16; ++kc) {
      const int ko = kc * 32;
      u16x8 b0h = *(const u16x8*)&sW[bof0 + ko];
      u16x8 b0l = *(const u16x8*)&sW[33024 + bof0 + ko];
      u16x8 b1h = *(const u16x8*)&sW[bof1 + ko];
      u16x8 b1l = *(const u16x8*)&sW[33024 + bof1 + ko];
      aq[0][kc & 1] = mfma16(oh[kc], b0h, aq[0][kc & 1]);
      aq[0][kc & 1] = mfma16(ol[kc], b0h, aq[0][kc & 1]);
      aq[0][kc & 1] = mfma16(oh[kc], b0l, aq[0][kc & 1]);
      aq[1][kc & 1] = mfma16(oh[kc], b1h, aq[1][kc & 1]);
      aq[1][kc & 1] = mfma16(ol[kc], b1h, aq[1][kc & 1]);
      aq[1][kc & 1] = mfma16(oh[kc], b1l, aq[1][kc & 1]);
    }
    f32x4 A0 = aq[0][0] + aq[0][1];
    f32x4 A1 = aq[1][0] + aq[1][1];

    __syncthreads();   // prev round's sg fully consumed
#pragma unroll
    for (int r4 = 0; r4 < 4; ++r4) {
      int m = mt * 16 + l4 * 4 + r4;
      sg[kh][m][l15] = A0[r4];
      sg[kh][m][16 + l15] = A1[r4];
    }
    __syncthreads();   // sg ready

    // ---- pointwise on all 512 threads ----
    float g0 = sg[0][pb][uu] + sg[1][pb][uu];
    float g1 = sg[0][pb][8 + uu] + sg[1][pb][8 + uu];
    float g2 = sg[0][pb][16 + uu] + sg[1][pb][16 + uu];
    float g3 = sg[0][pb][24 + uu] + sg[1][pb][24 + uu];
    waitcnt0();  // px ready
    g0 += px0; g1 += px1; g2 += px2; g3 += px3;
    c = sigmoidf_(g1) * c + sigmoidf_(g0) * tanhf(g2);
    float h = sigmoidf_(g3) * tanhf(c);
    u32 hiu = (u32)f2bf(h);
    u32 lou = (u32)f2bf(h - bf2f((u16)hiu));
    // pack pairs, then gather 4 packed words to the uu==0 lane for a 16B store
    u32 pH = hiu | (__shfl_down(hiu, 1) << 16);
    u32 pL = lou | (__shfl_down(lou, 1) << 16);
    u32 qH1 = __shfl_down(pH, 2), qH2 = __shfl_down(pH, 4), qH3 = __shfl_down(pH, 6);
    u32 qL1 = __shfl_down(pL, 2), qL2 = __shfl_down(pL, 4), qL3 = __shfl_down(pL, 6);
    if ((tid & 7) == 0) {
      size_t re = (size_t)t * 65536 + (size_t)pb * 1024 + u0;
      store16_cc(ringH + re, pH, qH1, qH2, qH3);
      store16_cc(ringL + re, pL, qL1, qL2, qL3);
      if (t == TC - 1) {
        size_t ce = (size_t)pb * 1024 + u0;
        store16_cc(carryH + ce, pH, qH1, qH2, qH3);
        store16_cc(carryL + ce, pL, qL1, qL2, qL3);
      }
    }
    if (hfinal && t == TC - 1) hfinal[cidx] = h;

    // ---- drain own wave's stores, raise own flag ----
    waitcnt0();
    if (lane == 0) store4_cc_u32(fown, (u32)(t + 1));
  }

  cbp[cidx] = c;
}

// ---------- MLP (fp32 vector) ----------
__global__ void k_fc(const float* __restrict__ in, const float* __restrict__ W,
                     const float* __restrict__ bias, float* __restrict__ out,
                     int K, int N, int relu) {
  int b = blockIdx.x;
  int n = blockIdx.y * 256 + threadIdx.x;
  if (n >= N) return;
  const float4* wr = (const float4*)(W + (size_t)n * K);
  const float4* xr = (const float4*)(in + (size_t)b * K);
  float s = 0.f;
  for (int k = 0; k < K / 4; ++k) {
    float4 w = wr[k], x = xr[k];
    s += w.x * x.x + w.y * x.y + w.z * x.z + w.w * x.w;
  }
  s += bias[n];
  if (relu) s = fmaxf(s, 0.f);
  out[(size_t)b * N + n] = s;
}

__global__ void k_out(const float* __restrict__ z, const float* __restrict__ W3,
                      const float* __restrict__ b3, float* __restrict__ outp) {
  int b = blockIdx.x;
  int lane = threadIdx.x;  // 64
  const float4* wr = (const float4*)W3;
  const float4* xr = (const float4*)(z + b * 512);
  float s = 0.f;
  for (int k = lane; k < 128; k += 64) {
    float4 w = wr[k], x = xr[k];
    s += w.x * x.x + w.y * x.y + w.z * x.z + w.w * x.w;
  }
  for (int off = 32; off; off >>= 1) s += __shfl_down(s, off);
  if (lane == 0) outp[b] = s + b3[0];
}

// ---------- launch ----------
extern "C" void kernel_launch(void* const* d_in, const int* in_sizes, int n_in,
                              void* d_out, int out_size, void* d_ws, size_t ws_size,
                              hipStream_t stream) {
  (void)in_sizes; (void)n_in; (void)out_size; (void)ws_size;
  const float* xx  = (const float*)d_in[0];
  const float* W10 = (const float*)d_in[1];
  const float* b10i = (const float*)d_in[2];
  const float* b10h = (const float*)d_in[3];
  const float* W11 = (const float*)d_in[4];
  const float* b11i = (const float*)d_in[5];
  const float* b11h = (const float*)d_in[6];
  const float* W20 = (const float*)d_in[7];
  const float* Wh0 = (const float*)d_in[8];
  const float* b20i = (const float*)d_in[9];
  const float* b20h = (const float*)d_in[10];
  const float* W21 = (const float*)d_in[11];
  const float* Wh1 = (const float*)d_in[12];
  const float* b21i = (const float*)d_in[13];
  const float* b21h = (const float*)d_in[14];
  const float* mW1 = (const float*)d_in[15];
  const float* mb1 = (const float*)d_in[16];
  const float* mW2 = (const float*)d_in[17];
  const float* mb2 = (const float*)d_in[18];
  const float* mW3 = (const float*)d_in[19];
  const float* mb3 = (const float*)d_in[20];

  char* ws = (char*)d_ws;
  size_t o = 0;
  float* XG0 = (float*)(ws + o); o += (size_t)MC * G4 * 4;           // 32 MiB (l2-0 gates)
  float* XG1 = (float*)(ws + o); o += (size_t)MC * G4 * 4;           // 32 MiB (l2-1 gates)
  u16* Aah = (u16*)(ws + o); o += (size_t)MC * H_ * 2;               // l1-0 h / h1 ring
  u16* Aal = (u16*)(ws + o); o += (size_t)MC * H_ * 2;
  u16* Abh = (u16*)(ws + o); o += (size_t)MC * H_ * 2;               // l1-1 h / h0 ring
  u16* Abl = (u16*)(ws + o); o += (size_t)MC * H_ * 2;
  u16* XXh = (u16*)(ws + o); o += (size_t)MC * D_ * 2;
  u16* XXl = (u16*)(ws + o); o += (size_t)MC * D_ * 2;
  u16* W10h = (u16*)(ws + o); o += (size_t)G4 * D_ * 2;
  u16* W10l = (u16*)(ws + o); o += (size_t)G4 * D_ * 2;
  u16* W11h = (u16*)(ws + o); o += (size_t)G4 * H_ * 2;
  u16* W11l = (u16*)(ws + o); o += (size_t)G4 * H_ * 2;
  u16* W20h = (u16*)(ws + o); o += (size_t)G4 * H_ * 2;
  u16* W20l = (u16*)(ws + o); o += (size_t)G4 * H_ * 2;
  u16* Wh0h = (u16*)(ws + o); o += (size_t)G4 * H_ * 2;
  u16* Wh0l = (u16*)(ws + o); o += (size_t)G4 * H_ * 2;
  u16* W21h = (u16*)(ws + o); o += (size_t)G4 * H_ * 2;
  u16* W21l = (u16*)(ws + o); o += (size_t)G4 * H_ * 2;
  u16* Wh1h = (u16*)(ws + o); o += (size_t)G4 * H_ * 2;
  u16* Wh1l = (u16*)(ws + o); o += (size_t)G4 * H_ * 2;
  float* bs0 = (float*)(ws + o); o += G4 * 4;   // permuted (l1)
  float* bs1 = (float*)(ws + o); o += G4 * 4;   // permuted (l1)
  float* bs2 = (float*)(ws + o); o += G4 * 4;
  float* bs3 = (float*)(ws + o); o += G4 * 4;
  // state region (zeroed once per launch, contiguous)
  char* ST = ws + o;
  u16* h00H = (u16*)(ws + o); o += B_ * H_ * 2;
  u16* h00L = (u16*)(ws + o); o += B_ * H_ * 2;
  u16* h01H = (u16*)(ws + o); o += B_ * H_ * 2;
  u16* h01L = (u16*)(ws + o); o += B_ * H_ * 2;
  float* cb0 = (float*)(ws + o); o += B_ * H_ * 4;
  float* cb1 = (float*)(ws + o); o += B_ * H_ * 4;
  u32* FLG = (u32*)(ws + o); o += (NCHUNK + 1) * NFLG * 4;
  size_t stBytes = (size_t)((ws + o) - ST);
  float* FH = (float*)(ws + o); o += B_ * H_ * 4;
  float* Z1 = (float*)(ws + o); o += B_ * H_ * 4;
  float* Z2 = (float*)(ws + o); o += B_ * 512 * 4;

  // rings alias the l1 buffers (lifetimes: ring0=Ab consumed by XG1 GEMM before
  // next chunk's l1-1 GEMM rewrites Ab; ring1=Aa dead before l1-0 rewrites Aa).
  u16 *r0H = Abh, *r0L = Abl, *r1H = Aah, *r1L = Aal;

  // --- one-time weight/bias prep ---
  k_splitp<<<(G4 * D_ / 4 + 255) / 256, 256, 0, stream>>>(W10, W10h, W10l, G4 * D_ / 4, 6);
  k_splitp<<<(G4 * H_ / 4 + 255) / 256, 256, 0, stream>>>(W11, W11h, W11l, G4 * H_ / 4, 8);
  k_split<<<(G4 * H_ / 4 + 255) / 256, 256, 0, stream>>>(W20, W20h, W20l, G4 * H_ / 4);
  k_split<<<(G4 * H_ / 4 + 255) / 256, 256, 0, stream>>>(Wh0, Wh0h, Wh0l, G4 * H_ / 4);
  k_split<<<(G4 * H_ / 4 + 255) / 256, 256, 0, stream>>>(W21, W21h, W21l, G4 * H_ / 4);
  k_split<<<(G4 * H_ / 4 + 255) / 256, 256, 0, stream>>>(Wh1, Wh1h, Wh1l, G4 * H_ / 4);
  k_addp<<<16, 256, 0, stream>>>(b10i, b10h, bs0);
  k_addp<<<16, 256, 0, stream>>>(b11i, b11h, bs1);
  k_addvec<<<16, 256, 0, stream>>>(b20i, b20h, bs2, G4);
  k_addvec<<<16, 256, 0, stream>>>(b21i, b21h, bs3, G4);
  hipMemsetAsync(ST, 0, stBytes, stream);

  dim3 gg(MC / 128, G4 / 128);

  for (int c = 0; c < NCHUNK; ++c) {
    int t0 = c * TC;
    k_split_x<<<(MC * (D_ / 4) + 255) / 256, 256, 0, stream>>>(xx, XXh, XXl, t0);
    // l1 layer 0 (fused pointwise epilogue -> h planes in Aa)
    k_gemm3<<<gg, 256, 0, stream>>>(XXh, XXl, W10h, W10l, bs0, nullptr,
                                    Aah, Aal, MC, G4, D_, 3);
    // l1 layer 1 (fused -> Ab)
    k_gemm3<<<gg, 256, 0, stream>>>(Aah, Aal, W11h, W11l, bs1, nullptr,
                                    Abh, Abl, MC, G4, H_, 3);
    // l2-0 gates (rec layout, A rows b-major = l1 output)
    k_gemm3<<<gg, 256, 0, stream>>>(Abh, Abl, W20h, W20l, bs2, XG0,
                                    nullptr, nullptr, MC, G4, H_, 1);
    // dual dispatch: rec0(c) [half A] || rec1(c-1) [half B]
    k_recd<<<256, 512, 0, stream>>>(XG0, (c > 0) ? XG1 : nullptr,
                                    Wh0h, Wh0l, Wh1h, Wh1l,
                                    r0H, r0L, r1H, r1L,
                                    h00H, h00L, h01H, h01L, cb0, cb1,
                                    nullptr, FLG + c * NFLG);
    // l2-1 gates from the fresh h0 ring (rec layout, A rows t-major)
    k_gemm3<<<gg, 256, 0, stream>>>(r0H, r0L, W21h, W21l, bs3, XG1,
                                    nullptr, nullptr, MC, G4, H_, 2);
  }
  // tail: rec1(NCHUNK-1) alone [half B], writes FH
  k_recd<<<256, 512, 0, stream>>>(nullptr, XG1,
                                  Wh0h, Wh0l, Wh1h, Wh1l,
                                  r0H, r0L, r1H, r1L,
                                  h00H, h00L, h01H, h01L, cb0, cb1,
                                  FH, FLG + NCHUNK * NFLG);

  // MLP
  k_fc<<<dim3(B_, 4), 256, 0, stream>>>(FH, mW1, mb1, Z1, H_, H_, 1);
  k_fc<<<dim3(B_, 2), 256, 0, stream>>>(Z1, mW2, mb2, Z2, H_, 512, 1);
  k_out<<<B_, 64, 0, stream>>>(Z2, mW3, mb3, (float*)d_out);
}